// Round 4
// baseline (1041.284 us; speedup 1.0000x reference)
//
#include <hip/hip_runtime.h>

// ---------------------------------------------------------------------------
// ReactionGCN: 3-layer GCN (GCNConv + BN + ReLU) -> global_mean_pool -> MLP
// bf16 activations end-to-end (fp32 accumulation everywhere):
//   - GEMM = MFMA 16x16x32 bf16, BN affine folded into weights (k_foldW)
//   - aggregation gathers bf16 rows, recomputes edge weight from dis[]
//   - BN stats fused into aggregation epilogue
// CSR built on-device each call (src-only records to minimize scatter writes).
// ---------------------------------------------------------------------------

typedef __attribute__((ext_vector_type(8))) short short8;
typedef __attribute__((ext_vector_type(4))) float f32x4;

__device__ inline unsigned f32_to_bf16_rne(float f) {
  unsigned u = __float_as_uint(f);
  unsigned r = 0x7fffu + ((u >> 16) & 1u);
  return (u + r) >> 16;
}
__device__ inline unsigned pack2_bf16(float lo, float hi) {
  return f32_to_bf16_rne(lo) | (f32_to_bf16_rne(hi) << 16);
}
__device__ inline float bf16_lo(unsigned u) { return __uint_as_float(u << 16); }
__device__ inline float bf16_hi(unsigned u) { return __uint_as_float(u & 0xffff0000u); }

// zero a[na], b[nb], c[nc] in one launch
__global__ __launch_bounds__(256) void k_zero3(int* __restrict__ a, int na,
                                               int* __restrict__ b, int nb,
                                               int* __restrict__ c, int nc) {
  int i = blockIdx.x * blockDim.x + threadIdx.x;
  if (i < na) a[i] = 0;
  if (i < nb) b[i] = 0;
  if (i < nc) c[i] = 0;
}

__global__ __launch_bounds__(256) void k_hist_edges(const int* __restrict__ dst,
                                                    int* __restrict__ deg, int E) {
  for (int e = blockIdx.x * blockDim.x + threadIdx.x; e < E; e += gridDim.x * blockDim.x)
    atomicAdd(&deg[dst[e]], 1);
}

__global__ __launch_bounds__(256) void k_hist_batch(const int* __restrict__ batch,
                                                    int* __restrict__ cnt, int N) {
  int i = blockIdx.x * blockDim.x + threadIdx.x;
  if (i < N) atomicAdd(&cnt[batch[i]], 1);
}

__global__ __launch_bounds__(256) void k_dis(const int* __restrict__ deg, float* __restrict__ dis, int N) {
  int i = blockIdx.x * blockDim.x + threadIdx.x;
  if (i < N) dis[i] = 1.0f / sqrtf((float)deg[i] + 1.0f);
}

// -------------------- exclusive scan (3-kernel) ----------------------------
__global__ __launch_bounds__(256) void k_scan_partial(const int* __restrict__ in,
                                                      int* __restrict__ bsum, int n) {
  int t = threadIdx.x;
  int base = blockIdx.x * 1024 + t * 4;
  int v0 = (base     < n) ? in[base]     : 0;
  int v1 = (base + 1 < n) ? in[base + 1] : 0;
  int v2 = (base + 2 < n) ? in[base + 2] : 0;
  int v3 = (base + 3 < n) ? in[base + 3] : 0;
  int s = v0 + v1 + v2 + v3;
  for (int d = 32; d; d >>= 1) s += __shfl_down(s, d);
  __shared__ int wsh[4];
  int lane = t & 63, wv = t >> 6;
  if (lane == 0) wsh[wv] = s;
  __syncthreads();
  if (t == 0) bsum[blockIdx.x] = wsh[0] + wsh[1] + wsh[2] + wsh[3];
}

__global__ void k_scan_mid(int* __restrict__ bsum, int nb, int* __restrict__ total_out) {
  if (blockIdx.x == 0 && threadIdx.x == 0) {
    int run = 0;
    for (int i = 0; i < nb; ++i) { int t = bsum[i]; bsum[i] = run; run += t; }
    *total_out = run;
  }
}

__global__ __launch_bounds__(256) void k_scan_final(const int* __restrict__ in,
                                                    const int* __restrict__ bsum,
                                                    int* __restrict__ out, int n) {
  int t = threadIdx.x, lane = t & 63, wv = t >> 6;
  int base = blockIdx.x * 1024 + t * 4;
  int v0 = (base     < n) ? in[base]     : 0;
  int v1 = (base + 1 < n) ? in[base + 1] : 0;
  int v2 = (base + 2 < n) ? in[base + 2] : 0;
  int v3 = (base + 3 < n) ? in[base + 3] : 0;
  int tsum = v0 + v1 + v2 + v3;
  int x = tsum;
  for (int d = 1; d < 64; d <<= 1) { int y = __shfl_up(x, d); if (lane >= d) x += y; }
  __shared__ int wsum[4];
  if (lane == 63) wsum[wv] = x;
  __syncthreads();
  int woff = bsum[blockIdx.x];
  for (int w = 0; w < wv; ++w) woff += wsum[w];
  int excl = woff + x - tsum;
  if (base     < n) out[base]     = excl;
  if (base + 1 < n) out[base + 1] = excl + v0;
  if (base + 2 < n) out[base + 2] = excl + v0 + v1;
  if (base + 3 < n) out[base + 3] = excl + v0 + v1 + v2;
}

// -------------------- CSR fill (src index only) -----------------------------
__global__ __launch_bounds__(256) void k_csr_fill(const int* __restrict__ src,
                                                  const int* __restrict__ dst,
                                                  const int* __restrict__ eoff,
                                                  int* __restrict__ cursor,
                                                  int* __restrict__ csr_src, int E) {
  for (int e = blockIdx.x * blockDim.x + threadIdx.x; e < E; e += gridDim.x * blockDim.x) {
    int s = src[e], d = dst[e];
    int pos = eoff[d] + atomicAdd(&cursor[d], 1);
    csr_src[pos] = s;
  }
}

__global__ void k_init_aff(float* __restrict__ a, float* __restrict__ c) {
  int i = threadIdx.x;  // 128
  a[i] = 1.0f; c[i] = 0.0f;
}

// -------------------- fold BN affine into weights ---------------------------
// Blocks 0-7: pack W'[k,c]=a[k]*W[k,c] (bf16) in MFMA B-fragment order:
//   uint4 index (kstep*8+ct)*64+lane holds 8 bf16: j0..3 -> k=kb+j,
//   j4..7 -> k=kb+16+(j-4), kb=kstep*32+(lane>>4)*4, col=ct*16+(lane&15).
// Block 8: bias2[c] = sum_k c[k]*W[k,c]
__global__ __launch_bounds__(256) void k_foldW(const float* __restrict__ W,
                                               const float* __restrict__ aff_a,
                                               const float* __restrict__ aff_c,
                                               unsigned* __restrict__ Wp,
                                               float* __restrict__ bias2) {
  int blk = blockIdx.x;
  if (blk < 8) {
    int t = threadIdx.x;
    int kstep = t >> 6, lane = t & 63;
    int col = blk * 16 + (lane & 15);
    int kb = kstep * 32 + ((lane >> 4) << 2);
    unsigned o[4];
#pragma unroll
    for (int h = 0; h < 2; ++h) {
#pragma unroll
      for (int p = 0; p < 2; ++p) {
        int k0 = kb + h * 16 + p * 2;
        float w0 = aff_a[k0]     * W[(size_t)k0 * 128 + col];
        float w1 = aff_a[k0 + 1] * W[(size_t)(k0 + 1) * 128 + col];
        o[h * 2 + p] = pack2_bf16(w0, w1);
      }
    }
    *(uint4*)&Wp[((size_t)(kstep * 8 + blk) * 64 + lane) * 4] = make_uint4(o[0], o[1], o[2], o[3]);
  } else if (threadIdx.x < 128) {
    int c = threadIdx.x;
    float s = 0.f;
    for (int k = 0; k < 128; ++k) s = fmaf(aff_c[k], W[(size_t)k * 128 + c], s);
    bias2[c] = s;
  }
}

// -------------------- MFMA GEMM: out_bf16 = Xbf16 @ W' + bias2 --------------
// block = 256 thr (4 waves), tile 64 rows x 128 cols, K=128.
template <bool AFP32>
__global__ __launch_bounds__(256) void k_gemm_mfma(const void* __restrict__ Xv,
                                                   const unsigned* __restrict__ Wp,
                                                   const float* __restrict__ bias2,
                                                   unsigned* __restrict__ outb, int nrows) {
  __shared__ __align__(16) unsigned char Asm[64 * 256];  // 16KB bf16 rows, XOR-swizzled
  __shared__ uint4 Bsm[2048];                            // 32KB fragment-packed W'
  int t = threadIdx.x;
  int row0 = blockIdx.x * 64;
  for (int i = t; i < 2048; i += 256) Bsm[i] = ((const uint4*)Wp)[i];
  if (AFP32) {
    const float* X = (const float*)Xv;
    for (int idx = t; idx < 2048; idx += 256) {
      int r = idx >> 5, slot = idx & 31;
      int gr = row0 + r;
      float4 v = make_float4(0.f, 0.f, 0.f, 0.f);
      if (gr < nrows) v = *(const float4*)&X[(size_t)gr * 128 + slot * 4];
      int off = (slot * 8) ^ ((r & 7) << 4);
      *(uint2*)&Asm[r * 256 + off] = make_uint2(pack2_bf16(v.x, v.y), pack2_bf16(v.z, v.w));
    }
  } else {
    const uint4* X = (const uint4*)Xv;   // 16 uint4 per row
    for (int idx = t; idx < 1024; idx += 256) {
      int r = idx >> 4, slot = idx & 15;
      int gr = row0 + r;
      uint4 v = make_uint4(0, 0, 0, 0);
      if (gr < nrows) v = X[(size_t)gr * 16 + slot];
      int off = (slot * 16) ^ ((r & 7) << 4);
      *(uint4*)&Asm[r * 256 + off] = v;
    }
  }
  __syncthreads();

  int w = t >> 6, l = t & 63;
  int arow = w * 16 + (l & 15);
  int kgrp = l >> 4;
  int swz = (arow & 7) << 4;
  f32x4 acc[8];
#pragma unroll
  for (int i = 0; i < 8; ++i) acc[i] = (f32x4){0.f, 0.f, 0.f, 0.f};
#pragma unroll
  for (int kk = 0; kk < 4; ++kk) {
    int kb0 = kk * 64 + kgrp * 8;
    uint2 lo = *(uint2*)&Asm[arow * 256 + (kb0 ^ swz)];
    uint2 hi = *(uint2*)&Asm[arow * 256 + ((kb0 + 32) ^ swz)];
    union { uint4 u; short8 s; } af;
    af.u = make_uint4(lo.x, lo.y, hi.x, hi.y);
#pragma unroll
    for (int ct = 0; ct < 8; ++ct) {
      union { uint4 u; short8 s; } bf;
      bf.u = Bsm[(kk * 8 + ct) * 64 + l];
      acc[ct] = __builtin_amdgcn_mfma_f32_16x16x32_bf16(af.s, bf.s, acc[ct], 0, 0, 0);
    }
  }
  // D[row=(l>>4)*4+r][col=ct*16+(l&15)]
  int dcol = l & 15;
#pragma unroll
  for (int r = 0; r < 4; ++r) {
    int grow = row0 + w * 16 + kgrp * 4 + r;
    if (grow < nrows) {
#pragma unroll
      for (int ct = 0; ct < 8; ++ct) {
        int col = ct * 16 + dcol;
        float v = acc[ct][r] + bias2[col];
        ((unsigned short*)outb)[(size_t)grow * 128 + col] = (unsigned short)f32_to_bf16_rne(v);
      }
    }
  }
}

// -------------------- aggregation + fused BN stats --------------------------
// 64 nodes/block, wave w handles nodes base+4i+w. bf16 in, bf16 out.
#define AGG_CHUNK 64
__global__ __launch_bounds__(256) void k_aggregate(const unsigned* __restrict__ hWb,
                                                   const int* __restrict__ eoff,
                                                   const int* __restrict__ csr_src,
                                                   const float* __restrict__ dis,
                                                   const float* __restrict__ bias,
                                                   unsigned* __restrict__ h2b,
                                                   float* __restrict__ ssum,
                                                   float* __restrict__ ssq, int N) {
  int t = threadIdx.x, w = t >> 6, lane = t & 63;
  int base = blockIdx.x * AGG_CHUNK;
  float b0 = bias[2 * lane], b1 = bias[2 * lane + 1];
  float s0 = 0.f, q0 = 0.f, s1 = 0.f, q1 = 0.f;
  for (int i = 0; i < AGG_CHUNK / 4; ++i) {
    int node = base + i * 4 + w;
    if (node < N) {
      float dd = dis[node];
      float sn = dd * dd;
      unsigned su = hWb[(size_t)node * 64 + lane];
      float a0 = fmaf(bf16_lo(su), sn, b0);
      float a1 = fmaf(bf16_hi(su), sn, b1);
      int e0 = eoff[node], e1 = eoff[node + 1];
      if (e0 < e1) {
        int s_nxt = csr_src[e0];
        float d_nxt = dis[s_nxt];
        for (int p = e0; p < e1;) {
          int s_cur = s_nxt; float d_cur = d_nxt;
          ++p;
          if (p < e1) { s_nxt = csr_src[p]; d_nxt = dis[s_nxt]; }
          float wgt = d_cur * dd;
          unsigned u = hWb[(size_t)s_cur * 64 + lane];
          a0 = fmaf(wgt, bf16_lo(u), a0);
          a1 = fmaf(wgt, bf16_hi(u), a1);
        }
      }
      unsigned pk = pack2_bf16(fmaxf(a0, 0.f), fmaxf(a1, 0.f));
      h2b[(size_t)node * 64 + lane] = pk;
      float h0 = bf16_lo(pk), h1 = bf16_hi(pk);   // stats on rounded values
      s0 += h0; q0 = fmaf(h0, h0, q0);
      s1 += h1; q1 = fmaf(h1, h1, q1);
    }
  }
  __shared__ float red[4][256];
  red[0][t] = s0; red[1][t] = q0; red[2][t] = s1; red[3][t] = q1;
  __syncthreads();
  if (t < 64) {
    float S0 = red[0][t] + red[0][t + 64] + red[0][t + 128] + red[0][t + 192];
    float Q0 = red[1][t] + red[1][t + 64] + red[1][t + 128] + red[1][t + 192];
    float S1 = red[2][t] + red[2][t + 64] + red[2][t + 128] + red[2][t + 192];
    float Q1 = red[3][t] + red[3][t + 64] + red[3][t + 128] + red[3][t + 192];
    atomicAdd(&ssum[2 * t], S0);     atomicAdd(&ssum[2 * t + 1], S1);
    atomicAdd(&ssq[2 * t], Q0);      atomicAdd(&ssq[2 * t + 1], Q1);
  }
}

__global__ void k_finalize(const float* __restrict__ ssum, const float* __restrict__ ssq,
                           const float* __restrict__ gamma, const float* __restrict__ beta,
                           float* __restrict__ a, float* __restrict__ c, float invn) {
  int f = threadIdx.x;  // 128
  float mu  = ssum[f] * invn;
  float var = ssq[f] * invn - mu * mu;
  float s = gamma[f] / sqrtf(var + 1e-5f);
  a[f] = s;
  c[f] = beta[f] - mu * s;
}

// -------------------- pooling (one wave per graph, bf16 in) -----------------
__global__ __launch_bounds__(256) void k_pool(const unsigned* __restrict__ h2b,
                                              const int* __restrict__ goff,
                                              const float* __restrict__ a,
                                              const float* __restrict__ c,
                                              float* __restrict__ pooled, int G) {
  int g = (blockIdx.x * 256 + threadIdx.x) >> 6;
  int lane = threadIdx.x & 63;
  if (g >= G) return;
  int r0 = goff[g], r1 = goff[g + 1];
  float s0 = 0.f, s1 = 0.f;
  for (int r = r0; r < r1; ++r) {
    unsigned u = h2b[(size_t)r * 64 + lane];
    s0 += bf16_lo(u); s1 += bf16_hi(u);
  }
  float p0 = 0.f, p1 = 0.f;
  if (r1 > r0) {
    float inv = 1.0f / (float)(r1 - r0);
    p0 = fmaf(a[2 * lane],     s0 * inv, c[2 * lane]);
    p1 = fmaf(a[2 * lane + 1], s1 * inv, c[2 * lane + 1]);
  }
  *(float2*)&pooled[(size_t)g * 128 + 2 * lane] = make_float2(p0, p1);
}

// -------------------- final MLP (one wave per graph) ------------------------
__global__ __launch_bounds__(64) void k_mlp(const float* __restrict__ pooled,
                                            const float* __restrict__ hw1,
                                            const float* __restrict__ hb1,
                                            const float* __restrict__ hw2,
                                            const float* __restrict__ hb2,
                                            float* __restrict__ out, int G) {
  int g = blockIdx.x;
  int j = threadIdx.x;  // 64
  const float* p = pooled + (size_t)g * 128;
  float acc = hb1[j];
  for (int f = 0; f < 128; ++f) acc = fmaf(p[f], hw1[f * 64 + j], acc);
  acc = fmaxf(acc, 0.f) * hw2[j];
  for (int d = 32; d; d >>= 1) acc += __shfl_down(acc, d);
  if (j == 0) out[g] = acc + hb2[0];
}

// ---------------------------------------------------------------------------
extern "C" void kernel_launch(void* const* d_in, const int* in_sizes, int n_in,
                              void* d_out, int out_size, void* d_ws, size_t ws_size,
                              hipStream_t stream) {
  const float* x     = (const float*)d_in[0];
  const int*   ei    = (const int*)d_in[1];
  const int*   batch = (const int*)d_in[2];
  const float* W     = (const float*)d_in[3];
  const float* b     = (const float*)d_in[4];
  const float* gamma = (const float*)d_in[5];
  const float* beta  = (const float*)d_in[6];
  const float* hw1   = (const float*)d_in[7];
  const float* hb1   = (const float*)d_in[8];
  const float* hw2   = (const float*)d_in[9];
  const float* hb2   = (const float*)d_in[10];
  float* out = (float*)d_out;

  const int F = 128;
  const int N = in_sizes[0] / F;
  const int E = in_sizes[1] / 2;
  const int G = out_size;

  const int* esrc = ei;
  const int* edst = ei + E;

  // ---- workspace carve ----
  char* wp = (char*)d_ws;
  auto alloc = [&](size_t bytes) -> void* {
    void* r = (void*)wp;
    wp += (bytes + 255) & ~(size_t)255;
    return r;
  };
  unsigned* hWb   = (unsigned*)alloc((size_t)N * 64 * 4);   // bf16 [N][128]
  unsigned* h2b   = (unsigned*)alloc((size_t)N * 64 * 4);   // bf16 [N][128]
  float* dis      = (float*)alloc((size_t)N * 4);
  int*   deg      = (int*)alloc((size_t)N * 4);
  int*   eoff     = (int*)alloc((size_t)(N + 1) * 4);
  int*   cursor   = (int*)alloc((size_t)N * 4);
  int*   csr_src  = (int*)alloc((size_t)E * 4);
  int*   bsum     = (int*)alloc(1024 * 4);
  int*   gcnt     = (int*)alloc((size_t)G * 4);
  int*   goff     = (int*)alloc((size_t)(G + 1) * 4);
  float* ssum     = (float*)alloc(128 * 4);
  float* ssq      = (float*)alloc(128 * 4);   // contiguous after ssum
  float* aff_a    = (float*)alloc(128 * 4);
  float* aff_c    = (float*)alloc(128 * 4);
  unsigned* Wp    = (unsigned*)alloc(32768);
  float* bias2    = (float*)alloc(128 * 4);
  float* pooled   = (float*)alloc((size_t)G * F * 4);
  (void)ws_size; (void)n_in;

  auto cdiv = [](int a_, int b_) { return (a_ + b_ - 1) / b_; };

  // ---- graph structure (once) ----
  k_zero3<<<cdiv(N, 256), 256, 0, stream>>>(deg, N, cursor, N, gcnt, G);

  k_hist_edges<<<1024, 256, 0, stream>>>(edst, deg, E);
  k_dis<<<cdiv(N, 256), 256, 0, stream>>>(deg, dis, N);

  int nb1 = cdiv(N, 1024);
  k_scan_partial<<<nb1, 256, 0, stream>>>(deg, bsum, N);
  k_scan_mid<<<1, 1, 0, stream>>>(bsum, nb1, eoff + N);
  k_scan_final<<<nb1, 256, 0, stream>>>(deg, bsum, eoff, N);

  k_csr_fill<<<1024, 256, 0, stream>>>(esrc, edst, eoff, cursor, csr_src, E);

  k_hist_batch<<<cdiv(N, 256), 256, 0, stream>>>(batch, gcnt, N);
  int nb2 = cdiv(G, 1024);
  k_scan_partial<<<nb2, 256, 0, stream>>>(gcnt, bsum, G);
  k_scan_mid<<<1, 1, 0, stream>>>(bsum, nb2, goff + G);
  k_scan_final<<<nb2, 256, 0, stream>>>(gcnt, bsum, goff, G);

  k_init_aff<<<1, 128, 0, stream>>>(aff_a, aff_c);

  // ---- 3 GCN layers ----
  for (int i = 0; i < 3; ++i) {
    k_foldW<<<9, 256, 0, stream>>>(W + (size_t)i * F * F, aff_a, aff_c, Wp, bias2);
    if (i == 0)
      k_gemm_mfma<true><<<cdiv(N, 64), 256, 0, stream>>>(x, Wp, bias2, hWb, N);
    else
      k_gemm_mfma<false><<<cdiv(N, 64), 256, 0, stream>>>(h2b, Wp, bias2, hWb, N);
    k_zero3<<<1, 256, 0, stream>>>((int*)ssum, 256, (int*)ssum, 0, (int*)ssum, 0);
    k_aggregate<<<cdiv(N, AGG_CHUNK), 256, 0, stream>>>(hWb, eoff, csr_src, dis,
                                                        b + (size_t)i * F, h2b, ssum, ssq, N);
    k_finalize<<<1, 128, 0, stream>>>(ssum, ssq, gamma + (size_t)i * F, beta + (size_t)i * F,
                                      aff_a, aff_c, 1.0f / (float)N);
  }

  // ---- pooling + MLP ----
  k_pool<<<cdiv(G * 64, 256), 256, 0, stream>>>(h2b, goff, aff_a, aff_c, pooled, G);
  k_mlp<<<G, 64, 0, stream>>>(pooled, hw1, hb1, hw2, hb2, out, G);
}

// Round 5
// 770.599 us; speedup vs baseline: 1.3513x; 1.3513x over previous
//
#include <hip/hip_runtime.h>

// ---------------------------------------------------------------------------
// ReactionGCN: 3-layer GCN (GCNConv + BN + ReLU) -> global_mean_pool -> MLP
// bf16 activations end-to-end (fp32 accumulation everywhere):
//   - GEMM = MFMA 16x16x32 bf16, BN affine folded into weights (k_foldW)
//   - aggregation: ONE WAVE PER NODE, bf16 row gathers, 2 rows in flight,
//     scalar (wave-uniform) index loads via readfirstlane
//   - BN stats: separate small kernel on bf16 h2 (25 MB)
// CSR built on-device each call (src-only records to minimize scatter writes).
// ---------------------------------------------------------------------------

typedef __attribute__((ext_vector_type(8))) short short8;
typedef __attribute__((ext_vector_type(4))) float f32x4;

__device__ inline unsigned f32_to_bf16_rne(float f) {
  unsigned u = __float_as_uint(f);
  unsigned r = 0x7fffu + ((u >> 16) & 1u);
  return (u + r) >> 16;
}
__device__ inline unsigned pack2_bf16(float lo, float hi) {
  return f32_to_bf16_rne(lo) | (f32_to_bf16_rne(hi) << 16);
}
__device__ inline float bf16_lo(unsigned u) { return __uint_as_float(u << 16); }
__device__ inline float bf16_hi(unsigned u) { return __uint_as_float(u & 0xffff0000u); }

// zero a[na], b[nb], c[nc] in one launch
__global__ __launch_bounds__(256) void k_zero3(int* __restrict__ a, int na,
                                               int* __restrict__ b, int nb,
                                               int* __restrict__ c, int nc) {
  int i = blockIdx.x * blockDim.x + threadIdx.x;
  if (i < na) a[i] = 0;
  if (i < nb) b[i] = 0;
  if (i < nc) c[i] = 0;
}

__global__ __launch_bounds__(256) void k_hist_edges(const int* __restrict__ dst,
                                                    int* __restrict__ deg, int E) {
  for (int e = blockIdx.x * blockDim.x + threadIdx.x; e < E; e += gridDim.x * blockDim.x)
    atomicAdd(&deg[dst[e]], 1);
}

__global__ __launch_bounds__(256) void k_hist_batch(const int* __restrict__ batch,
                                                    int* __restrict__ cnt, int N) {
  int i = blockIdx.x * blockDim.x + threadIdx.x;
  if (i < N) atomicAdd(&cnt[batch[i]], 1);
}

__global__ __launch_bounds__(256) void k_dis(const int* __restrict__ deg, float* __restrict__ dis, int N) {
  int i = blockIdx.x * blockDim.x + threadIdx.x;
  if (i < N) dis[i] = 1.0f / sqrtf((float)deg[i] + 1.0f);
}

// -------------------- exclusive scan (3-kernel) ----------------------------
__global__ __launch_bounds__(256) void k_scan_partial(const int* __restrict__ in,
                                                      int* __restrict__ bsum, int n) {
  int t = threadIdx.x;
  int base = blockIdx.x * 1024 + t * 4;
  int v0 = (base     < n) ? in[base]     : 0;
  int v1 = (base + 1 < n) ? in[base + 1] : 0;
  int v2 = (base + 2 < n) ? in[base + 2] : 0;
  int v3 = (base + 3 < n) ? in[base + 3] : 0;
  int s = v0 + v1 + v2 + v3;
  for (int d = 32; d; d >>= 1) s += __shfl_down(s, d);
  __shared__ int wsh[4];
  int lane = t & 63, wv = t >> 6;
  if (lane == 0) wsh[wv] = s;
  __syncthreads();
  if (t == 0) bsum[blockIdx.x] = wsh[0] + wsh[1] + wsh[2] + wsh[3];
}

__global__ void k_scan_mid(int* __restrict__ bsum, int nb, int* __restrict__ total_out) {
  if (blockIdx.x == 0 && threadIdx.x == 0) {
    int run = 0;
    for (int i = 0; i < nb; ++i) { int t = bsum[i]; bsum[i] = run; run += t; }
    *total_out = run;
  }
}

__global__ __launch_bounds__(256) void k_scan_final(const int* __restrict__ in,
                                                    const int* __restrict__ bsum,
                                                    int* __restrict__ out, int n) {
  int t = threadIdx.x, lane = t & 63, wv = t >> 6;
  int base = blockIdx.x * 1024 + t * 4;
  int v0 = (base     < n) ? in[base]     : 0;
  int v1 = (base + 1 < n) ? in[base + 1] : 0;
  int v2 = (base + 2 < n) ? in[base + 2] : 0;
  int v3 = (base + 3 < n) ? in[base + 3] : 0;
  int tsum = v0 + v1 + v2 + v3;
  int x = tsum;
  for (int d = 1; d < 64; d <<= 1) { int y = __shfl_up(x, d); if (lane >= d) x += y; }
  __shared__ int wsum[4];
  if (lane == 63) wsum[wv] = x;
  __syncthreads();
  int woff = bsum[blockIdx.x];
  for (int w = 0; w < wv; ++w) woff += wsum[w];
  int excl = woff + x - tsum;
  if (base     < n) out[base]     = excl;
  if (base + 1 < n) out[base + 1] = excl + v0;
  if (base + 2 < n) out[base + 2] = excl + v0 + v1;
  if (base + 3 < n) out[base + 3] = excl + v0 + v1 + v2;
}

// -------------------- CSR fill (src index only) -----------------------------
__global__ __launch_bounds__(256) void k_csr_fill(const int* __restrict__ src,
                                                  const int* __restrict__ dst,
                                                  const int* __restrict__ eoff,
                                                  int* __restrict__ cursor,
                                                  int* __restrict__ csr_src, int E) {
  for (int e = blockIdx.x * blockDim.x + threadIdx.x; e < E; e += gridDim.x * blockDim.x) {
    int s = src[e], d = dst[e];
    int pos = eoff[d] + atomicAdd(&cursor[d], 1);
    csr_src[pos] = s;
  }
}

__global__ void k_init_aff(float* __restrict__ a, float* __restrict__ c) {
  int i = threadIdx.x;  // 128
  a[i] = 1.0f; c[i] = 0.0f;
}

// -------------------- fold BN affine into weights ---------------------------
// Blocks 0-7: pack W'[k,c]=a[k]*W[k,c] (bf16) in MFMA B-fragment order.
// Block 8: bias2[c] = sum_k c[k]*W[k,c]
__global__ __launch_bounds__(256) void k_foldW(const float* __restrict__ W,
                                               const float* __restrict__ aff_a,
                                               const float* __restrict__ aff_c,
                                               unsigned* __restrict__ Wp,
                                               float* __restrict__ bias2) {
  int blk = blockIdx.x;
  if (blk < 8) {
    int t = threadIdx.x;
    int kstep = t >> 6, lane = t & 63;
    int col = blk * 16 + (lane & 15);
    int kb = kstep * 32 + ((lane >> 4) << 2);
    unsigned o[4];
#pragma unroll
    for (int h = 0; h < 2; ++h) {
#pragma unroll
      for (int p = 0; p < 2; ++p) {
        int k0 = kb + h * 16 + p * 2;
        float w0 = aff_a[k0]     * W[(size_t)k0 * 128 + col];
        float w1 = aff_a[k0 + 1] * W[(size_t)(k0 + 1) * 128 + col];
        o[h * 2 + p] = pack2_bf16(w0, w1);
      }
    }
    *(uint4*)&Wp[((size_t)(kstep * 8 + blk) * 64 + lane) * 4] = make_uint4(o[0], o[1], o[2], o[3]);
  } else if (threadIdx.x < 128) {
    int c = threadIdx.x;
    float s = 0.f;
    for (int k = 0; k < 128; ++k) s = fmaf(aff_c[k], W[(size_t)k * 128 + c], s);
    bias2[c] = s;
  }
}

// -------------------- MFMA GEMM: out_bf16 = Xbf16 @ W' + bias2 --------------
// block = 256 thr (4 waves), tile 64 rows x 128 cols, K=128.
template <bool AFP32>
__global__ __launch_bounds__(256) void k_gemm_mfma(const void* __restrict__ Xv,
                                                   const unsigned* __restrict__ Wp,
                                                   const float* __restrict__ bias2,
                                                   unsigned* __restrict__ outb, int nrows) {
  __shared__ __align__(16) unsigned char Asm[64 * 256];  // 16KB bf16 rows, XOR-swizzled
  __shared__ uint4 Bsm[2048];                            // 32KB fragment-packed W'
  int t = threadIdx.x;
  int row0 = blockIdx.x * 64;
  for (int i = t; i < 2048; i += 256) Bsm[i] = ((const uint4*)Wp)[i];
  if (AFP32) {
    const float* X = (const float*)Xv;
    for (int idx = t; idx < 2048; idx += 256) {
      int r = idx >> 5, slot = idx & 31;
      int gr = row0 + r;
      float4 v = make_float4(0.f, 0.f, 0.f, 0.f);
      if (gr < nrows) v = *(const float4*)&X[(size_t)gr * 128 + slot * 4];
      int off = (slot * 8) ^ ((r & 7) << 4);
      *(uint2*)&Asm[r * 256 + off] = make_uint2(pack2_bf16(v.x, v.y), pack2_bf16(v.z, v.w));
    }
  } else {
    const uint4* X = (const uint4*)Xv;   // 16 uint4 per row
    for (int idx = t; idx < 1024; idx += 256) {
      int r = idx >> 4, slot = idx & 15;
      int gr = row0 + r;
      uint4 v = make_uint4(0, 0, 0, 0);
      if (gr < nrows) v = X[(size_t)gr * 16 + slot];
      int off = (slot * 16) ^ ((r & 7) << 4);
      *(uint4*)&Asm[r * 256 + off] = v;
    }
  }
  __syncthreads();

  int w = t >> 6, l = t & 63;
  int arow = w * 16 + (l & 15);
  int kgrp = l >> 4;
  int swz = (arow & 7) << 4;
  f32x4 acc[8];
#pragma unroll
  for (int i = 0; i < 8; ++i) acc[i] = (f32x4){0.f, 0.f, 0.f, 0.f};
#pragma unroll
  for (int kk = 0; kk < 4; ++kk) {
    int kb0 = kk * 64 + kgrp * 8;
    uint2 lo = *(uint2*)&Asm[arow * 256 + (kb0 ^ swz)];
    uint2 hi = *(uint2*)&Asm[arow * 256 + ((kb0 + 32) ^ swz)];
    union { uint4 u; short8 s; } af;
    af.u = make_uint4(lo.x, lo.y, hi.x, hi.y);
#pragma unroll
    for (int ct = 0; ct < 8; ++ct) {
      union { uint4 u; short8 s; } bf;
      bf.u = Bsm[(kk * 8 + ct) * 64 + l];
      acc[ct] = __builtin_amdgcn_mfma_f32_16x16x32_bf16(af.s, bf.s, acc[ct], 0, 0, 0);
    }
  }
  // D[row=(l>>4)*4+r][col=ct*16+(l&15)]
  int dcol = l & 15;
#pragma unroll
  for (int r = 0; r < 4; ++r) {
    int grow = row0 + w * 16 + kgrp * 4 + r;
    if (grow < nrows) {
#pragma unroll
      for (int ct = 0; ct < 8; ++ct) {
        int col = ct * 16 + dcol;
        float v = acc[ct][r] + bias2[col];
        ((unsigned short*)outb)[(size_t)grow * 128 + col] = (unsigned short)f32_to_bf16_rne(v);
      }
    }
  }
}

// -------------------- aggregation (one wave per dst node, bf16 rows) --------
// Scalar (wave-uniform) CSR/index loads; 2 row-gathers in flight.
__global__ __launch_bounds__(256) void k_aggregate(const unsigned* __restrict__ hWb,
                                                   const int* __restrict__ eoff,
                                                   const int* __restrict__ csr_src,
                                                   const float* __restrict__ dis,
                                                   const float* __restrict__ bias,
                                                   unsigned* __restrict__ h2b, int N) {
  int node = __builtin_amdgcn_readfirstlane((blockIdx.x * 256 + threadIdx.x) >> 6);
  int lane = threadIdx.x & 63;
  if (node >= N) return;
  float dd = dis[node];
  float sn = dd * dd;
  unsigned su = hWb[(size_t)node * 64 + lane];
  float a0 = fmaf(bf16_lo(su), sn, bias[2 * lane]);
  float a1 = fmaf(bf16_hi(su), sn, bias[2 * lane + 1]);
  int p  = eoff[node];
  int e1 = eoff[node + 1];
  int rem = e1 - p;
  while (rem >= 2) {
    int sA = csr_src[p], sB = csr_src[p + 1];
    p += 2; rem -= 2;
    float dA = dis[sA], dB = dis[sB];
    unsigned uA = hWb[(size_t)sA * 64 + lane];
    unsigned uB = hWb[(size_t)sB * 64 + lane];
    float wA = dA * dd, wB = dB * dd;
    a0 = fmaf(wA, bf16_lo(uA), a0);
    a1 = fmaf(wA, bf16_hi(uA), a1);
    a0 = fmaf(wB, bf16_lo(uB), a0);
    a1 = fmaf(wB, bf16_hi(uB), a1);
  }
  if (rem) {
    int sA = csr_src[p];
    float wA = dis[sA] * dd;
    unsigned uA = hWb[(size_t)sA * 64 + lane];
    a0 = fmaf(wA, bf16_lo(uA), a0);
    a1 = fmaf(wA, bf16_hi(uA), a1);
  }
  h2b[(size_t)node * 64 + lane] = pack2_bf16(fmaxf(a0, 0.f), fmaxf(a1, 0.f));
}

// -------------------- BN stats on bf16 h2 -----------------------------------
__global__ __launch_bounds__(256) void k_stats_b(const unsigned* __restrict__ h2b,
                                                 float* __restrict__ ssum,
                                                 float* __restrict__ ssq, int N) {
  int c = threadIdx.x & 63;   // uint column (2 features)
  int q = threadIdx.x >> 6;   // 0..3
  int r0 = blockIdx.x * 1024;
  int r1 = r0 + 1024; if (r1 > N) r1 = N;
  float s0 = 0.f, q0 = 0.f, s1 = 0.f, q1 = 0.f;
  for (int r = r0 + q; r < r1; r += 4) {
    unsigned u = h2b[(size_t)r * 64 + c];
    float h0 = bf16_lo(u), h1 = bf16_hi(u);
    s0 += h0; q0 = fmaf(h0, h0, q0);
    s1 += h1; q1 = fmaf(h1, h1, q1);
  }
  __shared__ float red[4][256];
  int t = threadIdx.x;
  red[0][t] = s0; red[1][t] = q0; red[2][t] = s1; red[3][t] = q1;
  __syncthreads();
  if (t < 64) {
    float S0 = red[0][t] + red[0][t + 64] + red[0][t + 128] + red[0][t + 192];
    float Q0 = red[1][t] + red[1][t + 64] + red[1][t + 128] + red[1][t + 192];
    float S1 = red[2][t] + red[2][t + 64] + red[2][t + 128] + red[2][t + 192];
    float Q1 = red[3][t] + red[3][t + 64] + red[3][t + 128] + red[3][t + 192];
    atomicAdd(&ssum[2 * t], S0);     atomicAdd(&ssum[2 * t + 1], S1);
    atomicAdd(&ssq[2 * t], Q0);      atomicAdd(&ssq[2 * t + 1], Q1);
  }
}

__global__ void k_finalize(const float* __restrict__ ssum, const float* __restrict__ ssq,
                           const float* __restrict__ gamma, const float* __restrict__ beta,
                           float* __restrict__ a, float* __restrict__ c, float invn) {
  int f = threadIdx.x;  // 128
  float mu  = ssum[f] * invn;
  float var = ssq[f] * invn - mu * mu;
  float s = gamma[f] / sqrtf(var + 1e-5f);
  a[f] = s;
  c[f] = beta[f] - mu * s;
}

// -------------------- pooling (one wave per graph, bf16 in) -----------------
__global__ __launch_bounds__(256) void k_pool(const unsigned* __restrict__ h2b,
                                              const int* __restrict__ goff,
                                              const float* __restrict__ a,
                                              const float* __restrict__ c,
                                              float* __restrict__ pooled, int G) {
  int g = __builtin_amdgcn_readfirstlane((blockIdx.x * 256 + threadIdx.x) >> 6);
  int lane = threadIdx.x & 63;
  if (g >= G) return;
  int r0 = goff[g], r1 = goff[g + 1];
  float s0 = 0.f, s1 = 0.f;
  for (int r = r0; r < r1; ++r) {
    unsigned u = h2b[(size_t)r * 64 + lane];
    s0 += bf16_lo(u); s1 += bf16_hi(u);
  }
  float p0 = 0.f, p1 = 0.f;
  if (r1 > r0) {
    float inv = 1.0f / (float)(r1 - r0);
    p0 = fmaf(a[2 * lane],     s0 * inv, c[2 * lane]);
    p1 = fmaf(a[2 * lane + 1], s1 * inv, c[2 * lane + 1]);
  }
  *(float2*)&pooled[(size_t)g * 128 + 2 * lane] = make_float2(p0, p1);
}

// -------------------- final MLP (one wave per graph) ------------------------
__global__ __launch_bounds__(64) void k_mlp(const float* __restrict__ pooled,
                                            const float* __restrict__ hw1,
                                            const float* __restrict__ hb1,
                                            const float* __restrict__ hw2,
                                            const float* __restrict__ hb2,
                                            float* __restrict__ out, int G) {
  int g = blockIdx.x;
  int j = threadIdx.x;  // 64
  const float* p = pooled + (size_t)g * 128;
  float acc = hb1[j];
  for (int f = 0; f < 128; ++f) acc = fmaf(p[f], hw1[f * 64 + j], acc);
  acc = fmaxf(acc, 0.f) * hw2[j];
  for (int d = 32; d; d >>= 1) acc += __shfl_down(acc, d);
  if (j == 0) out[g] = acc + hb2[0];
}

// ---------------------------------------------------------------------------
extern "C" void kernel_launch(void* const* d_in, const int* in_sizes, int n_in,
                              void* d_out, int out_size, void* d_ws, size_t ws_size,
                              hipStream_t stream) {
  const float* x     = (const float*)d_in[0];
  const int*   ei    = (const int*)d_in[1];
  const int*   batch = (const int*)d_in[2];
  const float* W     = (const float*)d_in[3];
  const float* b     = (const float*)d_in[4];
  const float* gamma = (const float*)d_in[5];
  const float* beta  = (const float*)d_in[6];
  const float* hw1   = (const float*)d_in[7];
  const float* hb1   = (const float*)d_in[8];
  const float* hw2   = (const float*)d_in[9];
  const float* hb2   = (const float*)d_in[10];
  float* out = (float*)d_out;

  const int F = 128;
  const int N = in_sizes[0] / F;
  const int E = in_sizes[1] / 2;
  const int G = out_size;

  const int* esrc = ei;
  const int* edst = ei + E;

  // ---- workspace carve ----
  char* wp = (char*)d_ws;
  auto alloc = [&](size_t bytes) -> void* {
    void* r = (void*)wp;
    wp += (bytes + 255) & ~(size_t)255;
    return r;
  };
  unsigned* hWb   = (unsigned*)alloc((size_t)N * 64 * 4);   // bf16 [N][128]
  unsigned* h2b   = (unsigned*)alloc((size_t)N * 64 * 4);   // bf16 [N][128]
  float* dis      = (float*)alloc((size_t)N * 4);
  int*   deg      = (int*)alloc((size_t)N * 4);
  int*   eoff     = (int*)alloc((size_t)(N + 1) * 4);
  int*   cursor   = (int*)alloc((size_t)N * 4);
  int*   csr_src  = (int*)alloc((size_t)E * 4);
  int*   bsum     = (int*)alloc(1024 * 4);
  int*   gcnt    = (int*)alloc((size_t)G * 4);
  int*   goff     = (int*)alloc((size_t)(G + 1) * 4);
  float* ssum     = (float*)alloc(128 * 4);
  float* ssq      = (float*)alloc(128 * 4);   // contiguous after ssum
  float* aff_a    = (float*)alloc(128 * 4);
  float* aff_c    = (float*)alloc(128 * 4);
  unsigned* Wp    = (unsigned*)alloc(32768);
  float* bias2    = (float*)alloc(128 * 4);
  float* pooled   = (float*)alloc((size_t)G * F * 4);
  (void)ws_size; (void)n_in;

  auto cdiv = [](int a_, int b_) { return (a_ + b_ - 1) / b_; };

  // ---- graph structure (once) ----
  k_zero3<<<cdiv(N, 256), 256, 0, stream>>>(deg, N, cursor, N, gcnt, G);

  k_hist_edges<<<1024, 256, 0, stream>>>(edst, deg, E);
  k_dis<<<cdiv(N, 256), 256, 0, stream>>>(deg, dis, N);

  int nb1 = cdiv(N, 1024);
  k_scan_partial<<<nb1, 256, 0, stream>>>(deg, bsum, N);
  k_scan_mid<<<1, 1, 0, stream>>>(bsum, nb1, eoff + N);
  k_scan_final<<<nb1, 256, 0, stream>>>(deg, bsum, eoff, N);

  k_csr_fill<<<1024, 256, 0, stream>>>(esrc, edst, eoff, cursor, csr_src, E);

  k_hist_batch<<<cdiv(N, 256), 256, 0, stream>>>(batch, gcnt, N);
  int nb2 = cdiv(G, 1024);
  k_scan_partial<<<nb2, 256, 0, stream>>>(gcnt, bsum, G);
  k_scan_mid<<<1, 1, 0, stream>>>(bsum, nb2, goff + G);
  k_scan_final<<<nb2, 256, 0, stream>>>(gcnt, bsum, goff, G);

  k_init_aff<<<1, 128, 0, stream>>>(aff_a, aff_c);

  // ---- 3 GCN layers ----
  for (int i = 0; i < 3; ++i) {
    k_foldW<<<9, 256, 0, stream>>>(W + (size_t)i * F * F, aff_a, aff_c, Wp, bias2);
    if (i == 0)
      k_gemm_mfma<true><<<cdiv(N, 64), 256, 0, stream>>>(x, Wp, bias2, hWb, N);
    else
      k_gemm_mfma<false><<<cdiv(N, 64), 256, 0, stream>>>(h2b, Wp, bias2, hWb, N);
    k_aggregate<<<cdiv(N * 64, 256), 256, 0, stream>>>(hWb, eoff, csr_src, dis,
                                                       b + (size_t)i * F, h2b, N);
    k_zero3<<<1, 256, 0, stream>>>((int*)ssum, 256, (int*)ssum, 0, (int*)ssum, 0);
    k_stats_b<<<cdiv(N, 1024), 256, 0, stream>>>(h2b, ssum, ssq, N);
    k_finalize<<<1, 128, 0, stream>>>(ssum, ssq, gamma + (size_t)i * F, beta + (size_t)i * F,
                                      aff_a, aff_c, 1.0f / (float)N);
  }

  // ---- pooling + MLP ----
  k_pool<<<cdiv(G * 64, 256), 256, 0, stream>>>(h2b, goff, aff_a, aff_c, pooled, G);
  k_mlp<<<G, 64, 0, stream>>>(pooled, hw1, hb1, hw2, hb2, out, G);
}

// Round 6
// 592.768 us; speedup vs baseline: 1.7566x; 1.3000x over previous
//
#include <hip/hip_runtime.h>

// ---------------------------------------------------------------------------
// ReactionGCN: 3-layer GCN (GCNConv + BN + ReLU) -> global_mean_pool -> MLP
// bf16 activations end-to-end (fp32 accumulation everywhere):
//   - GEMM = MFMA 16x16x32 bf16, BN affine folded into weights (k_foldW)
//   - aggregation: one wave per node, bf16 row gathers, 2 rows in flight
//   - CSR build: two-level counting sort (bucket = dst>>7, bucket regions
//     coincide with final CSR regions via eoff) -> coalesced scatter
// ---------------------------------------------------------------------------

typedef __attribute__((ext_vector_type(8))) short short8;
typedef __attribute__((ext_vector_type(4))) float f32x4;

__device__ inline unsigned f32_to_bf16_rne(float f) {
  unsigned u = __float_as_uint(f);
  unsigned r = 0x7fffu + ((u >> 16) & 1u);
  return (u + r) >> 16;
}
__device__ inline unsigned pack2_bf16(float lo, float hi) {
  return f32_to_bf16_rne(lo) | (f32_to_bf16_rne(hi) << 16);
}
__device__ inline float bf16_lo(unsigned u) { return __uint_as_float(u << 16); }
__device__ inline float bf16_hi(unsigned u) { return __uint_as_float(u & 0xffff0000u); }

// zero a[na], b[nb] in one launch
__global__ __launch_bounds__(256) void k_zero2(int* __restrict__ a, int na,
                                               int* __restrict__ b, int nb) {
  int i = blockIdx.x * blockDim.x + threadIdx.x;
  if (i < na) a[i] = 0;
  if (i < nb) b[i] = 0;
}

__global__ __launch_bounds__(256) void k_hist_edges(const int* __restrict__ dst,
                                                    int* __restrict__ deg, int E) {
  for (int e = blockIdx.x * blockDim.x + threadIdx.x; e < E; e += gridDim.x * blockDim.x)
    atomicAdd(&deg[dst[e]], 1);
}

__global__ __launch_bounds__(256) void k_hist_batch(const int* __restrict__ batch,
                                                    int* __restrict__ cnt, int N) {
  int i = blockIdx.x * blockDim.x + threadIdx.x;
  if (i < N) atomicAdd(&cnt[batch[i]], 1);
}

__global__ __launch_bounds__(256) void k_dis(const int* __restrict__ deg, float* __restrict__ dis, int N) {
  int i = blockIdx.x * blockDim.x + threadIdx.x;
  if (i < N) dis[i] = 1.0f / sqrtf((float)deg[i] + 1.0f);
}

// -------------------- exclusive scan (3-kernel) ----------------------------
__global__ __launch_bounds__(256) void k_scan_partial(const int* __restrict__ in,
                                                      int* __restrict__ bsum, int n) {
  int t = threadIdx.x;
  int base = blockIdx.x * 1024 + t * 4;
  int v0 = (base     < n) ? in[base]     : 0;
  int v1 = (base + 1 < n) ? in[base + 1] : 0;
  int v2 = (base + 2 < n) ? in[base + 2] : 0;
  int v3 = (base + 3 < n) ? in[base + 3] : 0;
  int s = v0 + v1 + v2 + v3;
  for (int d = 32; d; d >>= 1) s += __shfl_down(s, d);
  __shared__ int wsh[4];
  int lane = t & 63, wv = t >> 6;
  if (lane == 0) wsh[wv] = s;
  __syncthreads();
  if (t == 0) bsum[blockIdx.x] = wsh[0] + wsh[1] + wsh[2] + wsh[3];
}

__global__ void k_scan_mid(int* __restrict__ bsum, int nb, int* __restrict__ total_out) {
  if (blockIdx.x == 0 && threadIdx.x == 0) {
    int run = 0;
    for (int i = 0; i < nb; ++i) { int t = bsum[i]; bsum[i] = run; run += t; }
    *total_out = run;
  }
}

__global__ __launch_bounds__(256) void k_scan_final(const int* __restrict__ in,
                                                    const int* __restrict__ bsum,
                                                    int* __restrict__ out, int n) {
  int t = threadIdx.x, lane = t & 63, wv = t >> 6;
  int base = blockIdx.x * 1024 + t * 4;
  int v0 = (base     < n) ? in[base]     : 0;
  int v1 = (base + 1 < n) ? in[base + 1] : 0;
  int v2 = (base + 2 < n) ? in[base + 2] : 0;
  int v3 = (base + 3 < n) ? in[base + 3] : 0;
  int tsum = v0 + v1 + v2 + v3;
  int x = tsum;
  for (int d = 1; d < 64; d <<= 1) { int y = __shfl_up(x, d); if (lane >= d) x += y; }
  __shared__ int wsum[4];
  if (lane == 63) wsum[wv] = x;
  __syncthreads();
  int woff = bsum[blockIdx.x];
  for (int w = 0; w < wv; ++w) woff += wsum[w];
  int excl = woff + x - tsum;
  if (base     < n) out[base]     = excl;
  if (base + 1 < n) out[base + 1] = excl + v0;
  if (base + 2 < n) out[base + 2] = excl + v0 + v1;
  if (base + 3 < n) out[base + 3] = excl + v0 + v1 + v2;
}

// -------------------- bucket cursors init -----------------------------------
__global__ __launch_bounds__(256) void k_bcur_init(const int* __restrict__ eoff,
                                                   int* __restrict__ bcur, int N, int nbuk) {
  int b = blockIdx.x * 256 + threadIdx.x;
  if (b < nbuk) {
    int n0 = b * 128;
    bcur[b] = eoff[n0 > N ? N : n0];
  }
}

// -------------------- pass C: partition edges into bucket regions -----------
// chunk = 4096 edges/block; buckets regrouped in LDS -> coalesced runs out.
#define PCH 4096
#define NBUK_MAX 1024
__global__ __launch_bounds__(256) void k_partition(const int* __restrict__ src,
                                                   const int* __restrict__ dst,
                                                   int* __restrict__ bcur,
                                                   uint2* __restrict__ ebuf,
                                                   int E, int nbuk) {
  __shared__ int hist[NBUK_MAX];
  __shared__ int lofs[NBUK_MAX];
  __shared__ int gbase[NBUK_MAX];
  __shared__ uint2 stage[PCH];
  int t = threadIdx.x;
  int e0 = blockIdx.x * PCH;
  int cnt = E - e0; if (cnt > PCH) cnt = PCH;
  for (int i = t; i < nbuk; i += 256) hist[i] = 0;
  __syncthreads();
  uint2 ev[PCH / 256];
#pragma unroll
  for (int k = 0; k < PCH / 256; ++k) {
    int i = t + k * 256;
    uint2 r = make_uint2(0u, 0u);
    if (i < cnt) {
      r = make_uint2((unsigned)src[e0 + i], (unsigned)dst[e0 + i]);
      atomicAdd(&hist[r.y >> 7], 1);
    }
    ev[k] = r;
  }
  __syncthreads();
  // exclusive scan hist -> lofs (wave 0)
  if (t < 64) {
    int run = 0;
    for (int c0 = 0; c0 < nbuk; c0 += 64) {
      int idx = c0 + t;
      int v = (idx < nbuk) ? hist[idx] : 0;
      int x = v;
#pragma unroll
      for (int dlt = 1; dlt < 64; dlt <<= 1) { int y = __shfl_up(x, dlt); if (t >= dlt) x += y; }
      if (idx < nbuk) lofs[idx] = run + x - v;
      run += __shfl(x, 63);
    }
  }
  __syncthreads();
  // claim global space per bucket; reset hist for reuse as local cursor
  for (int i = t; i < nbuk; i += 256) {
    int h = hist[i];
    if (h > 0) gbase[i] = atomicAdd(&bcur[i], h);
    hist[i] = 0;
  }
  __syncthreads();
  // stage records grouped by bucket
#pragma unroll
  for (int k = 0; k < PCH / 256; ++k) {
    int i = t + k * 256;
    if (i < cnt) {
      uint2 r = ev[k];
      int bk = (int)(r.y >> 7);
      int rank = atomicAdd(&hist[bk], 1);
      stage[lofs[bk] + rank] = r;
    }
  }
  __syncthreads();
  // write out (consecutive j -> mostly consecutive global addresses)
  for (int j = t; j < cnt; j += 256) {
    uint2 r = stage[j];
    int bk = (int)(r.y >> 7);
    ebuf[(size_t)gbase[bk] + (j - lofs[bk])] = r;
  }
}

// -------------------- pass D: within-bucket CSR placement -------------------
__global__ __launch_bounds__(256) void k_bucket_csr(const uint2* __restrict__ ebuf,
                                                    const int* __restrict__ eoff,
                                                    int* __restrict__ csr_src, int N) {
  __shared__ int loff[129];
  __shared__ int lcur[128];
  int b = blockIdx.x;
  int n0 = b * 128;
  int t = threadIdx.x;
  int nn = N - n0; if (nn > 128) nn = 128;
  if (t <= nn) loff[t] = eoff[n0 + t];
  if (t < nn) lcur[t] = 0;
  __syncthreads();
  int e0 = loff[0], e1 = loff[nn];
  for (int j = e0 + t; j < e1; j += 256) {
    uint2 r = ebuf[j];
    int loc = (int)r.y - n0;
    int rank = atomicAdd(&lcur[loc], 1);
    csr_src[loff[loc] + rank] = (int)r.x;
  }
}

__global__ void k_init_aff(float* __restrict__ a, float* __restrict__ c) {
  int i = threadIdx.x;  // 128
  a[i] = 1.0f; c[i] = 0.0f;
}

// -------------------- fold BN affine into weights ---------------------------
// Blocks 0-7: pack W'[k,c]=a[k]*W[k,c] (bf16) in MFMA B-fragment order.
// Block 8: bias2[c] = sum_k c[k]*W[k,c]
__global__ __launch_bounds__(256) void k_foldW(const float* __restrict__ W,
                                               const float* __restrict__ aff_a,
                                               const float* __restrict__ aff_c,
                                               unsigned* __restrict__ Wp,
                                               float* __restrict__ bias2) {
  int blk = blockIdx.x;
  if (blk < 8) {
    int t = threadIdx.x;
    int kstep = t >> 6, lane = t & 63;
    int col = blk * 16 + (lane & 15);
    int kb = kstep * 32 + ((lane >> 4) << 2);
    unsigned o[4];
#pragma unroll
    for (int h = 0; h < 2; ++h) {
#pragma unroll
      for (int p = 0; p < 2; ++p) {
        int k0 = kb + h * 16 + p * 2;
        float w0 = aff_a[k0]     * W[(size_t)k0 * 128 + col];
        float w1 = aff_a[k0 + 1] * W[(size_t)(k0 + 1) * 128 + col];
        o[h * 2 + p] = pack2_bf16(w0, w1);
      }
    }
    *(uint4*)&Wp[((size_t)(kstep * 8 + blk) * 64 + lane) * 4] = make_uint4(o[0], o[1], o[2], o[3]);
  } else if (threadIdx.x < 128) {
    int c = threadIdx.x;
    float s = 0.f;
    for (int k = 0; k < 128; ++k) s = fmaf(aff_c[k], W[(size_t)k * 128 + c], s);
    bias2[c] = s;
  }
}

// -------------------- MFMA GEMM: out_bf16 = Xbf16 @ W' + bias2 --------------
// block = 256 thr (4 waves), tile 64 rows x 128 cols, K=128.
template <bool AFP32>
__global__ __launch_bounds__(256) void k_gemm_mfma(const void* __restrict__ Xv,
                                                   const unsigned* __restrict__ Wp,
                                                   const float* __restrict__ bias2,
                                                   unsigned* __restrict__ outb, int nrows) {
  __shared__ __align__(16) unsigned char Asm[64 * 256];  // 16KB bf16 rows, XOR-swizzled
  __shared__ uint4 Bsm[2048];                            // 32KB fragment-packed W'
  int t = threadIdx.x;
  int row0 = blockIdx.x * 64;
  for (int i = t; i < 2048; i += 256) Bsm[i] = ((const uint4*)Wp)[i];
  if (AFP32) {
    const float* X = (const float*)Xv;
    for (int idx = t; idx < 2048; idx += 256) {
      int r = idx >> 5, slot = idx & 31;
      int gr = row0 + r;
      float4 v = make_float4(0.f, 0.f, 0.f, 0.f);
      if (gr < nrows) v = *(const float4*)&X[(size_t)gr * 128 + slot * 4];
      int off = (slot * 8) ^ ((r & 7) << 4);
      *(uint2*)&Asm[r * 256 + off] = make_uint2(pack2_bf16(v.x, v.y), pack2_bf16(v.z, v.w));
    }
  } else {
    const uint4* X = (const uint4*)Xv;   // 16 uint4 per row
    for (int idx = t; idx < 1024; idx += 256) {
      int r = idx >> 4, slot = idx & 15;
      int gr = row0 + r;
      uint4 v = make_uint4(0, 0, 0, 0);
      if (gr < nrows) v = X[(size_t)gr * 16 + slot];
      int off = (slot * 16) ^ ((r & 7) << 4);
      *(uint4*)&Asm[r * 256 + off] = v;
    }
  }
  __syncthreads();

  int w = t >> 6, l = t & 63;
  int arow = w * 16 + (l & 15);
  int kgrp = l >> 4;
  int swz = (arow & 7) << 4;
  f32x4 acc[8];
#pragma unroll
  for (int i = 0; i < 8; ++i) acc[i] = (f32x4){0.f, 0.f, 0.f, 0.f};
#pragma unroll
  for (int kk = 0; kk < 4; ++kk) {
    int kb0 = kk * 64 + kgrp * 8;
    uint2 lo = *(uint2*)&Asm[arow * 256 + (kb0 ^ swz)];
    uint2 hi = *(uint2*)&Asm[arow * 256 + ((kb0 + 32) ^ swz)];
    union { uint4 u; short8 s; } af;
    af.u = make_uint4(lo.x, lo.y, hi.x, hi.y);
#pragma unroll
    for (int ct = 0; ct < 8; ++ct) {
      union { uint4 u; short8 s; } bf;
      bf.u = Bsm[(kk * 8 + ct) * 64 + l];
      acc[ct] = __builtin_amdgcn_mfma_f32_16x16x32_bf16(af.s, bf.s, acc[ct], 0, 0, 0);
    }
  }
  // D[row=(l>>4)*4+r][col=ct*16+(l&15)]
  int dcol = l & 15;
#pragma unroll
  for (int r = 0; r < 4; ++r) {
    int grow = row0 + w * 16 + kgrp * 4 + r;
    if (grow < nrows) {
#pragma unroll
      for (int ct = 0; ct < 8; ++ct) {
        int col = ct * 16 + dcol;
        float v = acc[ct][r] + bias2[col];
        ((unsigned short*)outb)[(size_t)grow * 128 + col] = (unsigned short)f32_to_bf16_rne(v);
      }
    }
  }
}

// -------------------- aggregation (one wave per dst node, bf16 rows) --------
__global__ __launch_bounds__(256) void k_aggregate(const unsigned* __restrict__ hWb,
                                                   const int* __restrict__ eoff,
                                                   const int* __restrict__ csr_src,
                                                   const float* __restrict__ dis,
                                                   const float* __restrict__ bias,
                                                   unsigned* __restrict__ h2b, int N) {
  int node = __builtin_amdgcn_readfirstlane((blockIdx.x * 256 + threadIdx.x) >> 6);
  int lane = threadIdx.x & 63;
  if (node >= N) return;
  float dd = dis[node];
  float sn = dd * dd;
  unsigned su = hWb[(size_t)node * 64 + lane];
  float a0 = fmaf(bf16_lo(su), sn, bias[2 * lane]);
  float a1 = fmaf(bf16_hi(su), sn, bias[2 * lane + 1]);
  int p  = eoff[node];
  int e1 = eoff[node + 1];
  int rem = e1 - p;
  while (rem >= 2) {
    int sA = csr_src[p], sB = csr_src[p + 1];
    p += 2; rem -= 2;
    float dA = dis[sA], dB = dis[sB];
    unsigned uA = hWb[(size_t)sA * 64 + lane];
    unsigned uB = hWb[(size_t)sB * 64 + lane];
    float wA = dA * dd, wB = dB * dd;
    a0 = fmaf(wA, bf16_lo(uA), a0);
    a1 = fmaf(wA, bf16_hi(uA), a1);
    a0 = fmaf(wB, bf16_lo(uB), a0);
    a1 = fmaf(wB, bf16_hi(uB), a1);
  }
  if (rem) {
    int sA = csr_src[p];
    float wA = dis[sA] * dd;
    unsigned uA = hWb[(size_t)sA * 64 + lane];
    a0 = fmaf(wA, bf16_lo(uA), a0);
    a1 = fmaf(wA, bf16_hi(uA), a1);
  }
  h2b[(size_t)node * 64 + lane] = pack2_bf16(fmaxf(a0, 0.f), fmaxf(a1, 0.f));
}

// -------------------- BN stats on bf16 h2 -----------------------------------
__global__ __launch_bounds__(256) void k_stats_b(const unsigned* __restrict__ h2b,
                                                 float* __restrict__ ssum,
                                                 float* __restrict__ ssq, int N) {
  int c = threadIdx.x & 63;   // uint column (2 features)
  int q = threadIdx.x >> 6;   // 0..3
  int r0 = blockIdx.x * 256;
  int r1 = r0 + 256; if (r1 > N) r1 = N;
  float s0 = 0.f, q0 = 0.f, s1 = 0.f, q1 = 0.f;
  for (int r = r0 + q; r < r1; r += 4) {
    unsigned u = h2b[(size_t)r * 64 + c];
    float h0 = bf16_lo(u), h1 = bf16_hi(u);
    s0 += h0; q0 = fmaf(h0, h0, q0);
    s1 += h1; q1 = fmaf(h1, h1, q1);
  }
  __shared__ float red[4][256];
  int t = threadIdx.x;
  red[0][t] = s0; red[1][t] = q0; red[2][t] = s1; red[3][t] = q1;
  __syncthreads();
  if (t < 64) {
    float S0 = red[0][t] + red[0][t + 64] + red[0][t + 128] + red[0][t + 192];
    float Q0 = red[1][t] + red[1][t + 64] + red[1][t + 128] + red[1][t + 192];
    float S1 = red[2][t] + red[2][t + 64] + red[2][t + 128] + red[2][t + 192];
    float Q1 = red[3][t] + red[3][t + 64] + red[3][t + 128] + red[3][t + 192];
    atomicAdd(&ssum[2 * t], S0);     atomicAdd(&ssum[2 * t + 1], S1);
    atomicAdd(&ssq[2 * t], Q0);      atomicAdd(&ssq[2 * t + 1], Q1);
  }
}

__global__ void k_finalize(const float* __restrict__ ssum, const float* __restrict__ ssq,
                           const float* __restrict__ gamma, const float* __restrict__ beta,
                           float* __restrict__ a, float* __restrict__ c, float invn) {
  int f = threadIdx.x;  // 128
  float mu  = ssum[f] * invn;
  float var = ssq[f] * invn - mu * mu;
  float s = gamma[f] / sqrtf(var + 1e-5f);
  a[f] = s;
  c[f] = beta[f] - mu * s;
}

// -------------------- pooling (one wave per graph, bf16 in) -----------------
__global__ __launch_bounds__(256) void k_pool(const unsigned* __restrict__ h2b,
                                              const int* __restrict__ goff,
                                              const float* __restrict__ a,
                                              const float* __restrict__ c,
                                              float* __restrict__ pooled, int G) {
  int g = __builtin_amdgcn_readfirstlane((blockIdx.x * 256 + threadIdx.x) >> 6);
  int lane = threadIdx.x & 63;
  if (g >= G) return;
  int r0 = goff[g], r1 = goff[g + 1];
  float s0 = 0.f, s1 = 0.f;
  for (int r = r0; r < r1; ++r) {
    unsigned u = h2b[(size_t)r * 64 + lane];
    s0 += bf16_lo(u); s1 += bf16_hi(u);
  }
  float p0 = 0.f, p1 = 0.f;
  if (r1 > r0) {
    float inv = 1.0f / (float)(r1 - r0);
    p0 = fmaf(a[2 * lane],     s0 * inv, c[2 * lane]);
    p1 = fmaf(a[2 * lane + 1], s1 * inv, c[2 * lane + 1]);
  }
  *(float2*)&pooled[(size_t)g * 128 + 2 * lane] = make_float2(p0, p1);
}

// -------------------- final MLP (one wave per graph) ------------------------
__global__ __launch_bounds__(64) void k_mlp(const float* __restrict__ pooled,
                                            const float* __restrict__ hw1,
                                            const float* __restrict__ hb1,
                                            const float* __restrict__ hw2,
                                            const float* __restrict__ hb2,
                                            float* __restrict__ out, int G) {
  int g = blockIdx.x;
  int j = threadIdx.x;  // 64
  const float* p = pooled + (size_t)g * 128;
  float acc = hb1[j];
  for (int f = 0; f < 128; ++f) acc = fmaf(p[f], hw1[f * 64 + j], acc);
  acc = fmaxf(acc, 0.f) * hw2[j];
  for (int d = 32; d; d >>= 1) acc += __shfl_down(acc, d);
  if (j == 0) out[g] = acc + hb2[0];
}

// ---------------------------------------------------------------------------
extern "C" void kernel_launch(void* const* d_in, const int* in_sizes, int n_in,
                              void* d_out, int out_size, void* d_ws, size_t ws_size,
                              hipStream_t stream) {
  const float* x     = (const float*)d_in[0];
  const int*   ei    = (const int*)d_in[1];
  const int*   batch = (const int*)d_in[2];
  const float* W     = (const float*)d_in[3];
  const float* b     = (const float*)d_in[4];
  const float* gamma = (const float*)d_in[5];
  const float* beta  = (const float*)d_in[6];
  const float* hw1   = (const float*)d_in[7];
  const float* hb1   = (const float*)d_in[8];
  const float* hw2   = (const float*)d_in[9];
  const float* hb2   = (const float*)d_in[10];
  float* out = (float*)d_out;

  const int F = 128;
  const int N = in_sizes[0] / F;
  const int E = in_sizes[1] / 2;
  const int G = out_size;
  const int nbuk = (N + 127) / 128;   // dst>>7 buckets (<=1024 for N<=131072)

  const int* esrc = ei;
  const int* edst = ei + E;

  // ---- workspace carve ----
  char* wp = (char*)d_ws;
  auto alloc = [&](size_t bytes) -> void* {
    void* r = (void*)wp;
    wp += (bytes + 255) & ~(size_t)255;
    return r;
  };
  unsigned* hWb   = (unsigned*)alloc((size_t)N * 64 * 4);   // bf16 [N][128]
  unsigned* h2b   = (unsigned*)alloc((size_t)N * 64 * 4);   // bf16 [N][128]
  float* dis      = (float*)alloc((size_t)N * 4);
  int*   deg      = (int*)alloc((size_t)N * 4);
  int*   eoff     = (int*)alloc((size_t)(N + 1) * 4);
  int*   csr_src  = (int*)alloc((size_t)E * 4);
  uint2* ebuf     = (uint2*)alloc((size_t)E * 8);
  int*   bcur     = (int*)alloc((size_t)NBUK_MAX * 4);
  int*   bsum     = (int*)alloc(1024 * 4);
  int*   gcnt     = (int*)alloc((size_t)G * 4);
  int*   goff     = (int*)alloc((size_t)(G + 1) * 4);
  float* ssum     = (float*)alloc(128 * 4);
  float* ssq      = (float*)alloc(128 * 4);   // contiguous after ssum
  float* aff_a    = (float*)alloc(128 * 4);
  float* aff_c    = (float*)alloc(128 * 4);
  unsigned* Wp    = (unsigned*)alloc(32768);
  float* bias2    = (float*)alloc(128 * 4);
  float* pooled   = (float*)alloc((size_t)G * F * 4);
  (void)ws_size; (void)n_in;

  auto cdiv = [](int a_, int b_) { return (a_ + b_ - 1) / b_; };

  // ---- graph structure (once) ----
  k_zero2<<<cdiv(N, 256), 256, 0, stream>>>(deg, N, gcnt, G);

  k_hist_edges<<<1024, 256, 0, stream>>>(edst, deg, E);
  k_dis<<<cdiv(N, 256), 256, 0, stream>>>(deg, dis, N);

  int nb1 = cdiv(N, 1024);
  k_scan_partial<<<nb1, 256, 0, stream>>>(deg, bsum, N);
  k_scan_mid<<<1, 1, 0, stream>>>(bsum, nb1, eoff + N);
  k_scan_final<<<nb1, 256, 0, stream>>>(deg, bsum, eoff, N);

  // two-level CSR build
  k_bcur_init<<<cdiv(nbuk, 256), 256, 0, stream>>>(eoff, bcur, N, nbuk);
  k_partition<<<cdiv(E, PCH), 256, 0, stream>>>(esrc, edst, bcur, ebuf, E, nbuk);
  k_bucket_csr<<<nbuk, 256, 0, stream>>>(ebuf, eoff, csr_src, N);

  k_hist_batch<<<cdiv(N, 256), 256, 0, stream>>>(batch, gcnt, N);
  int nb2 = cdiv(G, 1024);
  k_scan_partial<<<nb2, 256, 0, stream>>>(gcnt, bsum, G);
  k_scan_mid<<<1, 1, 0, stream>>>(bsum, nb2, goff + G);
  k_scan_final<<<nb2, 256, 0, stream>>>(gcnt, bsum, goff, G);

  k_init_aff<<<1, 128, 0, stream>>>(aff_a, aff_c);

  // ---- 3 GCN layers ----
  for (int i = 0; i < 3; ++i) {
    k_foldW<<<9, 256, 0, stream>>>(W + (size_t)i * F * F, aff_a, aff_c, Wp, bias2);
    if (i == 0)
      k_gemm_mfma<true><<<cdiv(N, 64), 256, 0, stream>>>(x, Wp, bias2, hWb, N);
    else
      k_gemm_mfma<false><<<cdiv(N, 64), 256, 0, stream>>>(h2b, Wp, bias2, hWb, N);
    k_aggregate<<<cdiv(N * 64, 256), 256, 0, stream>>>(hWb, eoff, csr_src, dis,
                                                       b + (size_t)i * F, h2b, N);
    k_zero2<<<1, 256, 0, stream>>>((int*)ssum, 256, (int*)ssum, 0);
    k_stats_b<<<cdiv(N, 256), 256, 0, stream>>>(h2b, ssum, ssq, N);
    k_finalize<<<1, 128, 0, stream>>>(ssum, ssq, gamma + (size_t)i * F, beta + (size_t)i * F,
                                      aff_a, aff_c, 1.0f / (float)N);
  }

  // ---- pooling + MLP ----
  k_pool<<<cdiv(G * 64, 256), 256, 0, stream>>>(h2b, goff, aff_a, aff_c, pooled, G);
  k_mlp<<<G, 64, 0, stream>>>(pooled, hw1, hb1, hw2, hb2, out, G);
}

// Round 7
// 507.206 us; speedup vs baseline: 2.0530x; 1.1687x over previous
//
#include <hip/hip_runtime.h>

// ---------------------------------------------------------------------------
// ReactionGCN: 3-layer GCN (GCNConv + BN + ReLU) -> global_mean_pool -> MLP
// bf16 activations end-to-end (fp32 accumulation):
//   - GEMM = MFMA 16x16x32 bf16; BN affine folded into weights; epilogue
//     pre-scales rows by dis[row] so aggregation is a pure unweighted sum
//   - aggregation: one wave per node, 8 bf16 row-gathers in flight
//   - CSR build: two-level counting sort with packed u32 records
//   - k_fold: finalize BN + fold W + bias2 + zero stats in ONE block
// ---------------------------------------------------------------------------

typedef __attribute__((ext_vector_type(8))) short short8;
typedef __attribute__((ext_vector_type(4))) float f32x4;

__device__ inline unsigned f32_to_bf16_rne(float f) {
  unsigned u = __float_as_uint(f);
  unsigned r = 0x7fffu + ((u >> 16) & 1u);
  return (u + r) >> 16;
}
__device__ inline unsigned pack2_bf16(float lo, float hi) {
  return f32_to_bf16_rne(lo) | (f32_to_bf16_rne(hi) << 16);
}
__device__ inline float bf16_lo(unsigned u) { return __uint_as_float(u << 16); }
__device__ inline float bf16_hi(unsigned u) { return __uint_as_float(u & 0xffff0000u); }

__global__ __launch_bounds__(256) void k_zero1(int* __restrict__ a, int na) {
  int i = blockIdx.x * blockDim.x + threadIdx.x;
  if (i < na) a[i] = 0;
}

__global__ __launch_bounds__(256) void k_hist_edges(const int* __restrict__ dst,
                                                    int* __restrict__ deg, int E) {
  for (int e = blockIdx.x * blockDim.x + threadIdx.x; e < E; e += gridDim.x * blockDim.x)
    atomicAdd(&deg[dst[e]], 1);
}

// -------------------- exclusive scan (3-kernel), final also emits dis -------
__global__ __launch_bounds__(256) void k_scan_partial(const int* __restrict__ in,
                                                      int* __restrict__ bsum, int n) {
  int t = threadIdx.x;
  int base = blockIdx.x * 1024 + t * 4;
  int v0 = (base     < n) ? in[base]     : 0;
  int v1 = (base + 1 < n) ? in[base + 1] : 0;
  int v2 = (base + 2 < n) ? in[base + 2] : 0;
  int v3 = (base + 3 < n) ? in[base + 3] : 0;
  int s = v0 + v1 + v2 + v3;
  for (int d = 32; d; d >>= 1) s += __shfl_down(s, d);
  __shared__ int wsh[4];
  int lane = t & 63, wv = t >> 6;
  if (lane == 0) wsh[wv] = s;
  __syncthreads();
  if (t == 0) bsum[blockIdx.x] = wsh[0] + wsh[1] + wsh[2] + wsh[3];
}

__global__ void k_scan_mid(int* __restrict__ bsum, int nb, int* __restrict__ total_out) {
  if (blockIdx.x == 0 && threadIdx.x == 0) {
    int run = 0;
    for (int i = 0; i < nb; ++i) { int t = bsum[i]; bsum[i] = run; run += t; }
    *total_out = run;
  }
}

__global__ __launch_bounds__(256) void k_scan_final_dis(const int* __restrict__ in,
                                                        const int* __restrict__ bsum,
                                                        int* __restrict__ out,
                                                        float* __restrict__ dis, int n) {
  int t = threadIdx.x, lane = t & 63, wv = t >> 6;
  int base = blockIdx.x * 1024 + t * 4;
  int v0 = (base     < n) ? in[base]     : 0;
  int v1 = (base + 1 < n) ? in[base + 1] : 0;
  int v2 = (base + 2 < n) ? in[base + 2] : 0;
  int v3 = (base + 3 < n) ? in[base + 3] : 0;
  int tsum = v0 + v1 + v2 + v3;
  int x = tsum;
  for (int d = 1; d < 64; d <<= 1) { int y = __shfl_up(x, d); if (lane >= d) x += y; }
  __shared__ int wsum[4];
  if (lane == 63) wsum[wv] = x;
  __syncthreads();
  int woff = bsum[blockIdx.x];
  for (int w = 0; w < wv; ++w) woff += wsum[w];
  int excl = woff + x - tsum;
  if (base     < n) { out[base]     = excl;                dis[base]     = 1.0f / sqrtf((float)v0 + 1.0f); }
  if (base + 1 < n) { out[base + 1] = excl + v0;           dis[base + 1] = 1.0f / sqrtf((float)v1 + 1.0f); }
  if (base + 2 < n) { out[base + 2] = excl + v0 + v1;      dis[base + 2] = 1.0f / sqrtf((float)v2 + 1.0f); }
  if (base + 3 < n) { out[base + 3] = excl + v0 + v1 + v2; dis[base + 3] = 1.0f / sqrtf((float)v3 + 1.0f); }
}

// -------------------- bucket cursors init -----------------------------------
__global__ __launch_bounds__(256) void k_bcur_init(const int* __restrict__ eoff,
                                                   int* __restrict__ bcur, int N, int nbuk) {
  int b = blockIdx.x * 256 + threadIdx.x;
  if (b < nbuk) {
    int n0 = b * 128;
    bcur[b] = eoff[n0 > N ? N : n0];
  }
}

// -------------------- pass C: partition edges into bucket regions -----------
// record = (src<<7) | (dst&127); bucket = dst>>7.
#define PCH 4096
#define NBUK_MAX 1024
__global__ __launch_bounds__(256) void k_partition(const int* __restrict__ src,
                                                   const int* __restrict__ dst,
                                                   int* __restrict__ bcur,
                                                   unsigned* __restrict__ ebuf,
                                                   int E, int nbuk) {
  __shared__ int hist[NBUK_MAX];
  __shared__ int lofs[NBUK_MAX];
  __shared__ int gbase[NBUK_MAX];
  __shared__ uint2 stage[PCH];
  int t = threadIdx.x;
  int e0 = blockIdx.x * PCH;
  int cnt = E - e0; if (cnt > PCH) cnt = PCH;
  for (int i = t; i < nbuk; i += 256) hist[i] = 0;
  __syncthreads();
  uint2 ev[PCH / 256];
#pragma unroll
  for (int k = 0; k < PCH / 256; ++k) {
    int i = t + k * 256;
    uint2 r = make_uint2(0u, 0u);
    if (i < cnt) {
      r = make_uint2((unsigned)src[e0 + i], (unsigned)dst[e0 + i]);
      atomicAdd(&hist[r.y >> 7], 1);
    }
    ev[k] = r;
  }
  __syncthreads();
  // exclusive scan hist -> lofs (wave 0)
  if (t < 64) {
    int run = 0;
    for (int c0 = 0; c0 < nbuk; c0 += 64) {
      int idx = c0 + t;
      int v = (idx < nbuk) ? hist[idx] : 0;
      int x = v;
#pragma unroll
      for (int dlt = 1; dlt < 64; dlt <<= 1) { int y = __shfl_up(x, dlt); if (t >= dlt) x += y; }
      if (idx < nbuk) lofs[idx] = run + x - v;
      run += __shfl(x, 63);
    }
  }
  __syncthreads();
  for (int i = t; i < nbuk; i += 256) {
    int h = hist[i];
    if (h > 0) gbase[i] = atomicAdd(&bcur[i], h);
    hist[i] = 0;
  }
  __syncthreads();
#pragma unroll
  for (int k = 0; k < PCH / 256; ++k) {
    int i = t + k * 256;
    if (i < cnt) {
      uint2 r = ev[k];
      int bk = (int)(r.y >> 7);
      unsigned packed = (r.x << 7) | (r.y & 127u);
      int rank = atomicAdd(&hist[bk], 1);
      stage[lofs[bk] + rank] = make_uint2(packed, (unsigned)bk);
    }
  }
  __syncthreads();
  for (int j = t; j < cnt; j += 256) {
    uint2 s = stage[j];
    int bk = (int)s.y;
    ebuf[(size_t)gbase[bk] + (j - lofs[bk])] = s.x;
  }
}

// -------------------- pass D: within-bucket CSR placement -------------------
__global__ __launch_bounds__(256) void k_bucket_csr(const unsigned* __restrict__ ebuf,
                                                    const int* __restrict__ eoff,
                                                    int* __restrict__ csr_src, int N) {
  __shared__ int loff[129];
  __shared__ int lcur[128];
  int b = blockIdx.x;
  int n0 = b * 128;
  int t = threadIdx.x;
  int nn = N - n0; if (nn > 128) nn = 128;
  if (t <= nn) loff[t] = eoff[n0 + t];
  if (t < nn) lcur[t] = 0;
  __syncthreads();
  int e0 = loff[0], e1 = loff[nn];
  for (int j = e0 + t; j < e1; j += 256) {
    unsigned r = ebuf[j];
    int loc = (int)(r & 127u);
    int rank = atomicAdd(&lcur[loc], 1);
    csr_src[loff[loc] + rank] = (int)(r >> 7);
  }
}

// -------------------- goff via binary search over sorted batch --------------
__global__ __launch_bounds__(256) void k_goff_bs(const int* __restrict__ batch,
                                                 int* __restrict__ goff, int N, int G) {
  int g = blockIdx.x * 256 + threadIdx.x;
  if (g > G) return;
  int lo = 0, hi = N;
  while (lo < hi) { int mid = (lo + hi) >> 1; if (batch[mid] < g) lo = mid + 1; else hi = mid; }
  goff[g] = lo;
}

// -------------------- fold: BN finalize + W fold + bias2 + stats zero -------
// MODE 0: identity affine, fold Wn. MODE 1: affine from stats, fold Wn.
// MODE 2: affine from stats only (no fold).
template <int MODE>
__global__ __launch_bounds__(256) void k_fold(const float* __restrict__ Wn,
                                              const float* __restrict__ gamma,
                                              const float* __restrict__ beta,
                                              float* __restrict__ ssum,
                                              float* __restrict__ ssq,
                                              unsigned* __restrict__ Wp,
                                              float* __restrict__ bias2,
                                              float* __restrict__ aff_a,
                                              float* __restrict__ aff_c,
                                              float invn) {
  __shared__ float as_[128], cs_[128], b2[128];
  int t = threadIdx.x;
  if (t < 128) {
    float a, c;
    if (MODE == 0) { a = 1.f; c = 0.f; }
    else {
      float mu  = ssum[t] * invn;
      float var = ssq[t] * invn - mu * mu;
      a = gamma[t] / sqrtf(var + 1e-5f);
      c = beta[t] - mu * a;
      ssum[t] = 0.f; ssq[t] = 0.f;
    }
    as_[t] = a; cs_[t] = c; b2[t] = 0.f;
    aff_a[t] = a; aff_c[t] = c;
  }
  __syncthreads();
  if (MODE < 2) {
#pragma unroll
    for (int it = 0; it < 8; ++it) {
      int item = it * 256 + t;
      int lane = item & 63, bk = (item >> 6) & 7, kstep = item >> 9;
      int col = bk * 16 + (lane & 15);
      int kb = kstep * 32 + ((lane >> 4) << 2);
      unsigned o[4];
      float bp = 0.f;
#pragma unroll
      for (int hh = 0; hh < 2; ++hh)
#pragma unroll
        for (int pp = 0; pp < 2; ++pp) {
          int k0 = kb + hh * 16 + pp * 2;
          float wA = Wn[(size_t)k0 * 128 + col];
          float wB = Wn[(size_t)(k0 + 1) * 128 + col];
          o[hh * 2 + pp] = pack2_bf16(as_[k0] * wA, as_[k0 + 1] * wB);
          bp = fmaf(cs_[k0], wA, fmaf(cs_[k0 + 1], wB, bp));
        }
      *(uint4*)&Wp[(size_t)item * 4] = make_uint4(o[0], o[1], o[2], o[3]);
      atomicAdd(&b2[col], bp);
    }
    __syncthreads();
    if (t < 128) bias2[t] = b2[t];
  }
}

// -------------------- MFMA GEMM: outb = bf16(dis[r] * (X @ W' + bias2)) -----
template <bool AFP32>
__global__ __launch_bounds__(256) void k_gemm_mfma(const void* __restrict__ Xv,
                                                   const unsigned* __restrict__ Wp,
                                                   const float* __restrict__ bias2,
                                                   const float* __restrict__ dis,
                                                   unsigned* __restrict__ outb, int nrows) {
  __shared__ __align__(16) unsigned char Asm[64 * 256];  // 16KB bf16 rows, XOR-swizzled
  __shared__ uint4 Bsm[2048];                            // 32KB fragment-packed W'
  int t = threadIdx.x;
  int row0 = blockIdx.x * 64;
  for (int i = t; i < 2048; i += 256) Bsm[i] = ((const uint4*)Wp)[i];
  if (AFP32) {
    const float* X = (const float*)Xv;
    for (int idx = t; idx < 2048; idx += 256) {
      int r = idx >> 5, slot = idx & 31;
      int gr = row0 + r;
      float4 v = make_float4(0.f, 0.f, 0.f, 0.f);
      if (gr < nrows) v = *(const float4*)&X[(size_t)gr * 128 + slot * 4];
      int off = (slot * 8) ^ ((r & 7) << 4);
      *(uint2*)&Asm[r * 256 + off] = make_uint2(pack2_bf16(v.x, v.y), pack2_bf16(v.z, v.w));
    }
  } else {
    const uint4* X = (const uint4*)Xv;
    for (int idx = t; idx < 1024; idx += 256) {
      int r = idx >> 4, slot = idx & 15;
      int gr = row0 + r;
      uint4 v = make_uint4(0, 0, 0, 0);
      if (gr < nrows) v = X[(size_t)gr * 16 + slot];
      int off = (slot * 16) ^ ((r & 7) << 4);
      *(uint4*)&Asm[r * 256 + off] = v;
    }
  }
  __syncthreads();

  int w = t >> 6, l = t & 63;
  int arow = w * 16 + (l & 15);
  int kgrp = l >> 4;
  int swz = (arow & 7) << 4;
  f32x4 acc[8];
#pragma unroll
  for (int i = 0; i < 8; ++i) acc[i] = (f32x4){0.f, 0.f, 0.f, 0.f};
#pragma unroll
  for (int kk = 0; kk < 4; ++kk) {
    int kb0 = kk * 64 + kgrp * 8;
    uint2 lo = *(uint2*)&Asm[arow * 256 + (kb0 ^ swz)];
    uint2 hi = *(uint2*)&Asm[arow * 256 + ((kb0 + 32) ^ swz)];
    union { uint4 u; short8 s; } af;
    af.u = make_uint4(lo.x, lo.y, hi.x, hi.y);
#pragma unroll
    for (int ct = 0; ct < 8; ++ct) {
      union { uint4 u; short8 s; } bf;
      bf.u = Bsm[(kk * 8 + ct) * 64 + l];
      acc[ct] = __builtin_amdgcn_mfma_f32_16x16x32_bf16(af.s, bf.s, acc[ct], 0, 0, 0);
    }
  }
  int dcol = l & 15;
#pragma unroll
  for (int r = 0; r < 4; ++r) {
    int grow = row0 + w * 16 + kgrp * 4 + r;
    if (grow < nrows) {
      float dr = dis[grow];
#pragma unroll
      for (int ct = 0; ct < 8; ++ct) {
        int col = ct * 16 + dcol;
        float v = (acc[ct][r] + bias2[col]) * dr;
        ((unsigned short*)outb)[(size_t)grow * 128 + col] = (unsigned short)f32_to_bf16_rne(v);
      }
    }
  }
}

// -------------------- aggregation (one wave per node, unweighted sums) ------
__global__ __launch_bounds__(256) void k_aggregate(const unsigned* __restrict__ hWb,
                                                   const int* __restrict__ eoff,
                                                   const int* __restrict__ csr_src,
                                                   const float* __restrict__ dis,
                                                   const float* __restrict__ bias,
                                                   unsigned* __restrict__ h2b, int N) {
  int node = __builtin_amdgcn_readfirstlane((int)((blockIdx.x * 256 + threadIdx.x) >> 6));
  int lane = threadIdx.x & 63;
  if (node >= N) return;
  unsigned su = hWb[(size_t)node * 64 + lane];
  float a0 = bf16_lo(su), a1 = bf16_hi(su);
  int p  = eoff[node];
  int e1 = eoff[node + 1];
  int rem = e1 - p;
  while (rem >= 8) {
    int s0 = csr_src[p+0], s1 = csr_src[p+1], s2 = csr_src[p+2], s3 = csr_src[p+3];
    int s4 = csr_src[p+4], s5 = csr_src[p+5], s6 = csr_src[p+6], s7 = csr_src[p+7];
    p += 8; rem -= 8;
    unsigned u0 = hWb[(size_t)s0 * 64 + lane], u1 = hWb[(size_t)s1 * 64 + lane];
    unsigned u2 = hWb[(size_t)s2 * 64 + lane], u3 = hWb[(size_t)s3 * 64 + lane];
    unsigned u4 = hWb[(size_t)s4 * 64 + lane], u5 = hWb[(size_t)s5 * 64 + lane];
    unsigned u6 = hWb[(size_t)s6 * 64 + lane], u7 = hWb[(size_t)s7 * 64 + lane];
    a0 += bf16_lo(u0); a1 += bf16_hi(u0);
    a0 += bf16_lo(u1); a1 += bf16_hi(u1);
    a0 += bf16_lo(u2); a1 += bf16_hi(u2);
    a0 += bf16_lo(u3); a1 += bf16_hi(u3);
    a0 += bf16_lo(u4); a1 += bf16_hi(u4);
    a0 += bf16_lo(u5); a1 += bf16_hi(u5);
    a0 += bf16_lo(u6); a1 += bf16_hi(u6);
    a0 += bf16_lo(u7); a1 += bf16_hi(u7);
  }
  while (rem >= 2) {
    int s0 = csr_src[p], s1 = csr_src[p + 1];
    p += 2; rem -= 2;
    unsigned u0 = hWb[(size_t)s0 * 64 + lane], u1 = hWb[(size_t)s1 * 64 + lane];
    a0 += bf16_lo(u0); a1 += bf16_hi(u0);
    a0 += bf16_lo(u1); a1 += bf16_hi(u1);
  }
  if (rem) {
    unsigned u0 = hWb[(size_t)csr_src[p] * 64 + lane];
    a0 += bf16_lo(u0); a1 += bf16_hi(u0);
  }
  float dd = dis[node];
  float2 bb = ((const float2*)bias)[lane];
  float v0 = fmaf(dd, a0, bb.x);
  float v1 = fmaf(dd, a1, bb.y);
  h2b[(size_t)node * 64 + lane] = pack2_bf16(fmaxf(v0, 0.f), fmaxf(v1, 0.f));
}

// -------------------- BN stats on bf16 h2 -----------------------------------
__global__ __launch_bounds__(256) void k_stats_b(const unsigned* __restrict__ h2b,
                                                 float* __restrict__ ssum,
                                                 float* __restrict__ ssq, int N) {
  int c = threadIdx.x & 63;
  int q = threadIdx.x >> 6;
  int r0 = blockIdx.x * 256;
  int r1 = r0 + 256; if (r1 > N) r1 = N;
  float s0 = 0.f, q0 = 0.f, s1 = 0.f, q1 = 0.f;
  for (int r = r0 + q; r < r1; r += 4) {
    unsigned u = h2b[(size_t)r * 64 + c];
    float h0 = bf16_lo(u), h1 = bf16_hi(u);
    s0 += h0; q0 = fmaf(h0, h0, q0);
    s1 += h1; q1 = fmaf(h1, h1, q1);
  }
  __shared__ float red[4][256];
  int t = threadIdx.x;
  red[0][t] = s0; red[1][t] = q0; red[2][t] = s1; red[3][t] = q1;
  __syncthreads();
  if (t < 64) {
    float S0 = red[0][t] + red[0][t + 64] + red[0][t + 128] + red[0][t + 192];
    float Q0 = red[1][t] + red[1][t + 64] + red[1][t + 128] + red[1][t + 192];
    float S1 = red[2][t] + red[2][t + 64] + red[2][t + 128] + red[2][t + 192];
    float Q1 = red[3][t] + red[3][t + 64] + red[3][t + 128] + red[3][t + 192];
    atomicAdd(&ssum[2 * t], S0);     atomicAdd(&ssum[2 * t + 1], S1);
    atomicAdd(&ssq[2 * t], Q0);      atomicAdd(&ssq[2 * t + 1], Q1);
  }
}

// -------------------- pooling (one wave per graph, 4-deep) ------------------
__global__ __launch_bounds__(256) void k_pool(const unsigned* __restrict__ h2b,
                                              const int* __restrict__ goff,
                                              const float* __restrict__ a,
                                              const float* __restrict__ c,
                                              float* __restrict__ pooled, int G) {
  int g = __builtin_amdgcn_readfirstlane((int)((blockIdx.x * 256 + threadIdx.x) >> 6));
  int lane = threadIdx.x & 63;
  if (g >= G) return;
  int r0 = goff[g], r1 = goff[g + 1];
  float s0 = 0.f, s1 = 0.f;
  int r = r0;
  while (r + 4 <= r1) {
    unsigned u0 = h2b[(size_t)(r + 0) * 64 + lane];
    unsigned u1 = h2b[(size_t)(r + 1) * 64 + lane];
    unsigned u2 = h2b[(size_t)(r + 2) * 64 + lane];
    unsigned u3 = h2b[(size_t)(r + 3) * 64 + lane];
    r += 4;
    s0 += bf16_lo(u0); s1 += bf16_hi(u0);
    s0 += bf16_lo(u1); s1 += bf16_hi(u1);
    s0 += bf16_lo(u2); s1 += bf16_hi(u2);
    s0 += bf16_lo(u3); s1 += bf16_hi(u3);
  }
  while (r < r1) {
    unsigned u = h2b[(size_t)r * 64 + lane];
    ++r;
    s0 += bf16_lo(u); s1 += bf16_hi(u);
  }
  float p0 = 0.f, p1 = 0.f;
  if (r1 > r0) {
    float inv = 1.0f / (float)(r1 - r0);
    float2 av = ((const float2*)a)[lane];
    float2 cv = ((const float2*)c)[lane];
    p0 = fmaf(av.x, s0 * inv, cv.x);
    p1 = fmaf(av.y, s1 * inv, cv.y);
  }
  *(float2*)&pooled[(size_t)g * 128 + 2 * lane] = make_float2(p0, p1);
}

// -------------------- final MLP (one wave per graph) ------------------------
__global__ __launch_bounds__(64) void k_mlp(const float* __restrict__ pooled,
                                            const float* __restrict__ hw1,
                                            const float* __restrict__ hb1,
                                            const float* __restrict__ hw2,
                                            const float* __restrict__ hb2,
                                            float* __restrict__ out, int G) {
  int g = blockIdx.x;
  int j = threadIdx.x;  // 64
  const float* p = pooled + (size_t)g * 128;
  float acc = hb1[j];
  for (int f = 0; f < 128; ++f) acc = fmaf(p[f], hw1[f * 64 + j], acc);
  acc = fmaxf(acc, 0.f) * hw2[j];
  for (int d = 32; d; d >>= 1) acc += __shfl_down(acc, d);
  if (j == 0) out[g] = acc + hb2[0];
}

// ---------------------------------------------------------------------------
extern "C" void kernel_launch(void* const* d_in, const int* in_sizes, int n_in,
                              void* d_out, int out_size, void* d_ws, size_t ws_size,
                              hipStream_t stream) {
  const float* x     = (const float*)d_in[0];
  const int*   ei    = (const int*)d_in[1];
  const int*   batch = (const int*)d_in[2];
  const float* W     = (const float*)d_in[3];
  const float* b     = (const float*)d_in[4];
  const float* gamma = (const float*)d_in[5];
  const float* beta  = (const float*)d_in[6];
  const float* hw1   = (const float*)d_in[7];
  const float* hb1   = (const float*)d_in[8];
  const float* hw2   = (const float*)d_in[9];
  const float* hb2   = (const float*)d_in[10];
  float* out = (float*)d_out;

  const int F = 128;
  const int N = in_sizes[0] / F;
  const int E = in_sizes[1] / 2;
  const int G = out_size;
  const int nbuk = (N + 127) / 128;

  const int* esrc = ei;
  const int* edst = ei + E;

  // ---- workspace carve ----
  char* wp = (char*)d_ws;
  auto alloc = [&](size_t bytes) -> void* {
    void* r = (void*)wp;
    wp += (bytes + 255) & ~(size_t)255;
    return r;
  };
  unsigned* hWb   = (unsigned*)alloc((size_t)N * 64 * 4);
  unsigned* h2b   = (unsigned*)alloc((size_t)N * 64 * 4);
  float* dis      = (float*)alloc((size_t)N * 4);
  int*   deg      = (int*)alloc((size_t)N * 4);
  int*   eoff     = (int*)alloc((size_t)(N + 1) * 4);
  int*   csr_src  = (int*)alloc((size_t)E * 4);
  unsigned* ebuf  = (unsigned*)alloc((size_t)E * 4);
  int*   bcur     = (int*)alloc((size_t)NBUK_MAX * 4);
  int*   bsum     = (int*)alloc(1024 * 4);
  int*   goff     = (int*)alloc((size_t)(G + 1) * 4);
  float* ssum     = (float*)alloc(128 * 4);
  float* ssq      = (float*)alloc(128 * 4);
  float* aff_a    = (float*)alloc(128 * 4);
  float* aff_c    = (float*)alloc(128 * 4);
  unsigned* Wp    = (unsigned*)alloc(32768);
  float* bias2    = (float*)alloc(128 * 4);
  float* pooled   = (float*)alloc((size_t)G * F * 4);
  (void)ws_size; (void)n_in;

  auto cdiv = [](int a_, int b_) { return (a_ + b_ - 1) / b_; };

  // ---- graph structure (once) ----
  k_zero1<<<cdiv(N, 256), 256, 0, stream>>>(deg, N);
  k_hist_edges<<<1024, 256, 0, stream>>>(edst, deg, E);

  int nb1 = cdiv(N, 1024);
  k_scan_partial<<<nb1, 256, 0, stream>>>(deg, bsum, N);
  k_scan_mid<<<1, 1, 0, stream>>>(bsum, nb1, eoff + N);
  k_scan_final_dis<<<nb1, 256, 0, stream>>>(deg, bsum, eoff, dis, N);

  k_bcur_init<<<cdiv(nbuk, 256), 256, 0, stream>>>(eoff, bcur, N, nbuk);
  k_partition<<<cdiv(E, PCH), 256, 0, stream>>>(esrc, edst, bcur, ebuf, E, nbuk);
  k_bucket_csr<<<nbuk, 256, 0, stream>>>(ebuf, eoff, csr_src, N);

  k_goff_bs<<<cdiv(G + 1, 256), 256, 0, stream>>>(batch, goff, N, G);

  // layer-0 fold (identity affine)
  k_fold<0><<<1, 256, 0, stream>>>(W, gamma, beta, ssum, ssq, Wp, bias2, aff_a, aff_c, 1.0f / (float)N);

  // ---- 3 GCN layers ----
  for (int i = 0; i < 3; ++i) {
    if (i == 0)
      k_gemm_mfma<true><<<cdiv(N, 64), 256, 0, stream>>>(x, Wp, bias2, dis, hWb, N);
    else
      k_gemm_mfma<false><<<cdiv(N, 64), 256, 0, stream>>>(h2b, Wp, bias2, dis, hWb, N);
    k_aggregate<<<cdiv(N * 64, 256), 256, 0, stream>>>(hWb, eoff, csr_src, dis,
                                                       b + (size_t)i * F, h2b, N);
    k_stats_b<<<cdiv(N, 256), 256, 0, stream>>>(h2b, ssum, ssq, N);
    if (i < 2)
      k_fold<1><<<1, 256, 0, stream>>>(W + (size_t)(i + 1) * F * F, gamma + (size_t)i * F,
                                       beta + (size_t)i * F, ssum, ssq, Wp, bias2,
                                       aff_a, aff_c, 1.0f / (float)N);
    else
      k_fold<2><<<1, 256, 0, stream>>>(W, gamma + (size_t)i * F, beta + (size_t)i * F,
                                       ssum, ssq, Wp, bias2, aff_a, aff_c, 1.0f / (float)N);
  }

  // ---- pooling + MLP ----
  k_pool<<<cdiv(G * 64, 256), 256, 0, stream>>>(h2b, goff, aff_a, aff_c, pooled, G);
  k_mlp<<<G, 64, 0, stream>>>(pooled, hw1, hb1, hw2, hb2, out, G);
}

// Round 8
// 439.671 us; speedup vs baseline: 2.3683x; 1.1536x over previous
//
#include <hip/hip_runtime.h>

// ---------------------------------------------------------------------------
// ReactionGCN: 3-layer GCN (GCNConv + BN + ReLU) -> global_mean_pool -> MLP
// bf16 activations end-to-end (fp32 accumulation):
//   - GEMM = MFMA 16x16x32 bf16; BN affine folded into weights; epilogue
//     pre-scales rows by dis[row] so aggregation is a pure unweighted sum
//   - aggregation: one wave per node, 8 bf16 row-gathers in flight
//   - CSR build: bucket counting sort; deg/eoff/dis derived inside the
//     bucket pass (NO per-edge global atomics anywhere)
// ---------------------------------------------------------------------------

typedef __attribute__((ext_vector_type(8))) short short8;
typedef __attribute__((ext_vector_type(4))) float f32x4;

__device__ inline unsigned f32_to_bf16_rne(float f) {
  unsigned u = __float_as_uint(f);
  unsigned r = 0x7fffu + ((u >> 16) & 1u);
  return (u + r) >> 16;
}
__device__ inline unsigned pack2_bf16(float lo, float hi) {
  return f32_to_bf16_rne(lo) | (f32_to_bf16_rne(hi) << 16);
}
__device__ inline float bf16_lo(unsigned u) { return __uint_as_float(u << 16); }
__device__ inline float bf16_hi(unsigned u) { return __uint_as_float(u & 0xffff0000u); }

#define PCH 4096
#define NBUK_MAX 1024

__global__ __launch_bounds__(256) void k_zero1(int* __restrict__ a, int na) {
  int i = blockIdx.x * blockDim.x + threadIdx.x;
  if (i < na) a[i] = 0;
}

// -------------------- bucket counts via LDS histogram -----------------------
__global__ __launch_bounds__(256) void k_bucket_cnt(const int* __restrict__ dst,
                                                    int* __restrict__ bcnt, int E, int nbuk) {
  __shared__ int hist[NBUK_MAX];
  int t = threadIdx.x;
  for (int i = t; i < nbuk; i += 256) hist[i] = 0;
  __syncthreads();
  for (int e = blockIdx.x * 256 + t; e < E; e += gridDim.x * 256)
    atomicAdd(&hist[((unsigned)dst[e]) >> 7], 1);
  __syncthreads();
  for (int i = t; i < nbuk; i += 256) {
    int h = hist[i];
    if (h) atomicAdd(&bcnt[i], h);
  }
}

// -------------------- single-block scan: bcnt -> bof, bcur ------------------
__global__ __launch_bounds__(256) void k_bof_scan(const int* __restrict__ bcnt,
                                                  int* __restrict__ bof,
                                                  int* __restrict__ bcur, int nbuk, int E) {
  int t = threadIdx.x;
  int base = t * 4;
  int v[4]; int s = 0;
#pragma unroll
  for (int k = 0; k < 4; ++k) { v[k] = (base + k < nbuk) ? bcnt[base + k] : 0; s += v[k]; }
  int lane = t & 63, wv = t >> 6;
  int x = s;
#pragma unroll
  for (int d = 1; d < 64; d <<= 1) { int y = __shfl_up(x, d); if (lane >= d) x += y; }
  __shared__ int wsum[4];
  if (lane == 63) wsum[wv] = x;
  __syncthreads();
  int woff = 0;
  for (int w = 0; w < wv; ++w) woff += wsum[w];
  int run = woff + x - s;
#pragma unroll
  for (int k = 0; k < 4; ++k) {
    if (base + k < nbuk) { bof[base + k] = run; bcur[base + k] = run; }
    run += v[k];
  }
  if (t == 0) bof[nbuk] = E;
}

// -------------------- pass C: partition edges into bucket regions -----------
// record = (src<<7) | (dst&127); bucket = dst>>7.
__global__ __launch_bounds__(256) void k_partition(const int* __restrict__ src,
                                                   const int* __restrict__ dst,
                                                   int* __restrict__ bcur,
                                                   unsigned* __restrict__ ebuf,
                                                   int E, int nbuk) {
  __shared__ int hist[NBUK_MAX];
  __shared__ int lofs[NBUK_MAX];
  __shared__ int gbase[NBUK_MAX];
  __shared__ uint2 stage[PCH];
  int t = threadIdx.x;
  int e0 = blockIdx.x * PCH;
  int cnt = E - e0; if (cnt > PCH) cnt = PCH;
  for (int i = t; i < nbuk; i += 256) hist[i] = 0;
  __syncthreads();
  uint2 ev[PCH / 256];
#pragma unroll
  for (int k = 0; k < PCH / 256; ++k) {
    int i = t + k * 256;
    uint2 r = make_uint2(0u, 0u);
    if (i < cnt) {
      r = make_uint2((unsigned)src[e0 + i], (unsigned)dst[e0 + i]);
      atomicAdd(&hist[r.y >> 7], 1);
    }
    ev[k] = r;
  }
  __syncthreads();
  if (t < 64) {
    int run = 0;
    for (int c0 = 0; c0 < nbuk; c0 += 64) {
      int idx = c0 + t;
      int v = (idx < nbuk) ? hist[idx] : 0;
      int x = v;
#pragma unroll
      for (int dlt = 1; dlt < 64; dlt <<= 1) { int y = __shfl_up(x, dlt); if (t >= dlt) x += y; }
      if (idx < nbuk) lofs[idx] = run + x - v;
      run += __shfl(x, 63);
    }
  }
  __syncthreads();
  for (int i = t; i < nbuk; i += 256) {
    int h = hist[i];
    if (h > 0) gbase[i] = atomicAdd(&bcur[i], h);
    hist[i] = 0;
  }
  __syncthreads();
#pragma unroll
  for (int k = 0; k < PCH / 256; ++k) {
    int i = t + k * 256;
    if (i < cnt) {
      uint2 r = ev[k];
      int bk = (int)(r.y >> 7);
      unsigned packed = (r.x << 7) | (r.y & 127u);
      int rank = atomicAdd(&hist[bk], 1);
      stage[lofs[bk] + rank] = make_uint2(packed, (unsigned)bk);
    }
  }
  __syncthreads();
  for (int j = t; j < cnt; j += 256) {
    uint2 s = stage[j];
    int bk = (int)s.y;
    ebuf[(size_t)gbase[bk] + (j - lofs[bk])] = s.x;
  }
}

// -------------------- pass D: fused deg/eoff/dis + CSR placement ------------
__global__ __launch_bounds__(256) void k_bucket_csr2(const unsigned* __restrict__ ebuf,
                                                     const int* __restrict__ bof,
                                                     int* __restrict__ eoff,
                                                     float* __restrict__ dis,
                                                     int* __restrict__ csr_src, int N, int E) {
  __shared__ int lcnt[128];
  __shared__ int loff[128];
  int b = blockIdx.x;
  int n0 = b * 128;
  int t = threadIdx.x;
  int nn = N - n0; if (nn > 128) nn = 128;
  int e0 = bof[b], e1 = bof[b + 1];
  if (t < 128) lcnt[t] = 0;
  __syncthreads();
  for (int j = e0 + t; j < e1; j += 256) atomicAdd(&lcnt[ebuf[j] & 127u], 1);
  __syncthreads();
  if (t < 64) {
    int run = 0;
    for (int c0 = 0; c0 < 128; c0 += 64) {
      int v = lcnt[c0 + t];
      int x = v;
#pragma unroll
      for (int d = 1; d < 64; d <<= 1) { int y = __shfl_up(x, d); if (t >= d) x += y; }
      loff[c0 + t] = run + x - v;
      run += __shfl(x, 63);
    }
  }
  __syncthreads();
  if (t < nn) {
    eoff[n0 + t] = e0 + loff[t];
    dis[n0 + t] = 1.0f / sqrtf((float)lcnt[t] + 1.0f);
  }
  if (b == (int)gridDim.x - 1 && t == nn) eoff[n0 + nn] = E;
  __syncthreads();
  if (t < 128) lcnt[t] = 0;   // reuse as cursor
  __syncthreads();
  for (int j = e0 + t; j < e1; j += 256) {
    unsigned r = ebuf[j];
    int loc = (int)(r & 127u);
    int rank = atomicAdd(&lcnt[loc], 1);
    csr_src[e0 + loff[loc] + rank] = (int)(r >> 7);
  }
}

// -------------------- goff via binary search over sorted batch --------------
__global__ __launch_bounds__(256) void k_goff_bs(const int* __restrict__ batch,
                                                 int* __restrict__ goff, int N, int G) {
  int g = blockIdx.x * 256 + threadIdx.x;
  if (g > G) return;
  int lo = 0, hi = N;
  while (lo < hi) { int mid = (lo + hi) >> 1; if (batch[mid] < g) lo = mid + 1; else hi = mid; }
  goff[g] = lo;
}

// -------------------- fold: BN finalize + W fold + bias2 + stats zero -------
// MODE 0: identity affine, fold Wn. MODE 1: affine from stats, fold Wn.
// MODE 2: affine from stats only (no fold).
template <int MODE>
__global__ __launch_bounds__(256) void k_fold(const float* __restrict__ Wn,
                                              const float* __restrict__ gamma,
                                              const float* __restrict__ beta,
                                              float* __restrict__ ssum,
                                              float* __restrict__ ssq,
                                              unsigned* __restrict__ Wp,
                                              float* __restrict__ bias2,
                                              float* __restrict__ aff_a,
                                              float* __restrict__ aff_c,
                                              float invn) {
  __shared__ float as_[128], cs_[128], b2[128];
  int t = threadIdx.x;
  if (t < 128) {
    float a, c;
    if (MODE == 0) { a = 1.f; c = 0.f; }
    else {
      float mu  = ssum[t] * invn;
      float var = ssq[t] * invn - mu * mu;
      a = gamma[t] / sqrtf(var + 1e-5f);
      c = beta[t] - mu * a;
      ssum[t] = 0.f; ssq[t] = 0.f;
    }
    as_[t] = a; cs_[t] = c; b2[t] = 0.f;
    aff_a[t] = a; aff_c[t] = c;
  }
  __syncthreads();
  if (MODE < 2) {
#pragma unroll
    for (int it = 0; it < 8; ++it) {
      int item = it * 256 + t;
      int lane = item & 63, bk = (item >> 6) & 7, kstep = item >> 9;
      int col = bk * 16 + (lane & 15);
      int kb = kstep * 32 + ((lane >> 4) << 2);
      unsigned o[4];
      float bp = 0.f;
#pragma unroll
      for (int hh = 0; hh < 2; ++hh)
#pragma unroll
        for (int pp = 0; pp < 2; ++pp) {
          int k0 = kb + hh * 16 + pp * 2;
          float wA = Wn[(size_t)k0 * 128 + col];
          float wB = Wn[(size_t)(k0 + 1) * 128 + col];
          o[hh * 2 + pp] = pack2_bf16(as_[k0] * wA, as_[k0 + 1] * wB);
          bp = fmaf(cs_[k0], wA, fmaf(cs_[k0 + 1], wB, bp));
        }
      *(uint4*)&Wp[(size_t)item * 4] = make_uint4(o[0], o[1], o[2], o[3]);
      atomicAdd(&b2[col], bp);
    }
    __syncthreads();
    if (t < 128) bias2[t] = b2[t];
  }
}

// -------------------- MFMA GEMM: outb = bf16(dis[r] * (X @ W' + bias2)) -----
template <bool AFP32>
__global__ __launch_bounds__(256) void k_gemm_mfma(const void* __restrict__ Xv,
                                                   const unsigned* __restrict__ Wp,
                                                   const float* __restrict__ bias2,
                                                   const float* __restrict__ dis,
                                                   unsigned* __restrict__ outb, int nrows) {
  __shared__ __align__(16) unsigned char Asm[64 * 256];  // 16KB bf16 rows, XOR-swizzled
  __shared__ uint4 Bsm[2048];                            // 32KB fragment-packed W'
  int t = threadIdx.x;
  int row0 = blockIdx.x * 64;
  for (int i = t; i < 2048; i += 256) Bsm[i] = ((const uint4*)Wp)[i];
  if (AFP32) {
    const float* X = (const float*)Xv;
    for (int idx = t; idx < 2048; idx += 256) {
      int r = idx >> 5, slot = idx & 31;
      int gr = row0 + r;
      float4 v = make_float4(0.f, 0.f, 0.f, 0.f);
      if (gr < nrows) v = *(const float4*)&X[(size_t)gr * 128 + slot * 4];
      int off = (slot * 8) ^ ((r & 7) << 4);
      *(uint2*)&Asm[r * 256 + off] = make_uint2(pack2_bf16(v.x, v.y), pack2_bf16(v.z, v.w));
    }
  } else {
    const uint4* X = (const uint4*)Xv;
    for (int idx = t; idx < 1024; idx += 256) {
      int r = idx >> 4, slot = idx & 15;
      int gr = row0 + r;
      uint4 v = make_uint4(0, 0, 0, 0);
      if (gr < nrows) v = X[(size_t)gr * 16 + slot];
      int off = (slot * 16) ^ ((r & 7) << 4);
      *(uint4*)&Asm[r * 256 + off] = v;
    }
  }
  __syncthreads();

  int w = t >> 6, l = t & 63;
  int arow = w * 16 + (l & 15);
  int kgrp = l >> 4;
  int swz = (arow & 7) << 4;
  f32x4 acc[8];
#pragma unroll
  for (int i = 0; i < 8; ++i) acc[i] = (f32x4){0.f, 0.f, 0.f, 0.f};
#pragma unroll
  for (int kk = 0; kk < 4; ++kk) {
    int kb0 = kk * 64 + kgrp * 8;
    uint2 lo = *(uint2*)&Asm[arow * 256 + (kb0 ^ swz)];
    uint2 hi = *(uint2*)&Asm[arow * 256 + ((kb0 + 32) ^ swz)];
    union { uint4 u; short8 s; } af;
    af.u = make_uint4(lo.x, lo.y, hi.x, hi.y);
#pragma unroll
    for (int ct = 0; ct < 8; ++ct) {
      union { uint4 u; short8 s; } bf;
      bf.u = Bsm[(kk * 8 + ct) * 64 + l];
      acc[ct] = __builtin_amdgcn_mfma_f32_16x16x32_bf16(af.s, bf.s, acc[ct], 0, 0, 0);
    }
  }
  int dcol = l & 15;
#pragma unroll
  for (int r = 0; r < 4; ++r) {
    int grow = row0 + w * 16 + kgrp * 4 + r;
    if (grow < nrows) {
      float dr = dis[grow];
#pragma unroll
      for (int ct = 0; ct < 8; ++ct) {
        int col = ct * 16 + dcol;
        float v = (acc[ct][r] + bias2[col]) * dr;
        ((unsigned short*)outb)[(size_t)grow * 128 + col] = (unsigned short)f32_to_bf16_rne(v);
      }
    }
  }
}

// -------------------- aggregation (one wave per node, unweighted sums) ------
__global__ __launch_bounds__(256) void k_aggregate(const unsigned* __restrict__ hWb,
                                                   const int* __restrict__ eoff,
                                                   const int* __restrict__ csr_src,
                                                   const float* __restrict__ dis,
                                                   const float* __restrict__ bias,
                                                   unsigned* __restrict__ h2b, int N) {
  int node = __builtin_amdgcn_readfirstlane((int)((blockIdx.x * 256 + threadIdx.x) >> 6));
  int lane = threadIdx.x & 63;
  if (node >= N) return;
  unsigned su = hWb[(size_t)node * 64 + lane];
  float a0 = bf16_lo(su), a1 = bf16_hi(su);
  int p  = eoff[node];
  int e1 = eoff[node + 1];
  int rem = e1 - p;
  while (rem >= 8) {
    int s0 = csr_src[p+0], s1 = csr_src[p+1], s2 = csr_src[p+2], s3 = csr_src[p+3];
    int s4 = csr_src[p+4], s5 = csr_src[p+5], s6 = csr_src[p+6], s7 = csr_src[p+7];
    p += 8; rem -= 8;
    unsigned u0 = hWb[(size_t)s0 * 64 + lane], u1 = hWb[(size_t)s1 * 64 + lane];
    unsigned u2 = hWb[(size_t)s2 * 64 + lane], u3 = hWb[(size_t)s3 * 64 + lane];
    unsigned u4 = hWb[(size_t)s4 * 64 + lane], u5 = hWb[(size_t)s5 * 64 + lane];
    unsigned u6 = hWb[(size_t)s6 * 64 + lane], u7 = hWb[(size_t)s7 * 64 + lane];
    a0 += bf16_lo(u0); a1 += bf16_hi(u0);
    a0 += bf16_lo(u1); a1 += bf16_hi(u1);
    a0 += bf16_lo(u2); a1 += bf16_hi(u2);
    a0 += bf16_lo(u3); a1 += bf16_hi(u3);
    a0 += bf16_lo(u4); a1 += bf16_hi(u4);
    a0 += bf16_lo(u5); a1 += bf16_hi(u5);
    a0 += bf16_lo(u6); a1 += bf16_hi(u6);
    a0 += bf16_lo(u7); a1 += bf16_hi(u7);
  }
  while (rem >= 2) {
    int s0 = csr_src[p], s1 = csr_src[p + 1];
    p += 2; rem -= 2;
    unsigned u0 = hWb[(size_t)s0 * 64 + lane], u1 = hWb[(size_t)s1 * 64 + lane];
    a0 += bf16_lo(u0); a1 += bf16_hi(u0);
    a0 += bf16_lo(u1); a1 += bf16_hi(u1);
  }
  if (rem) {
    unsigned u0 = hWb[(size_t)csr_src[p] * 64 + lane];
    a0 += bf16_lo(u0); a1 += bf16_hi(u0);
  }
  float dd = dis[node];
  float2 bb = ((const float2*)bias)[lane];
  float v0 = fmaf(dd, a0, bb.x);
  float v1 = fmaf(dd, a1, bb.y);
  h2b[(size_t)node * 64 + lane] = pack2_bf16(fmaxf(v0, 0.f), fmaxf(v1, 0.f));
}

// -------------------- BN stats on bf16 h2 -----------------------------------
__global__ __launch_bounds__(256) void k_stats_b(const unsigned* __restrict__ h2b,
                                                 float* __restrict__ ssum,
                                                 float* __restrict__ ssq, int N) {
  int c = threadIdx.x & 63;
  int q = threadIdx.x >> 6;
  int r0 = blockIdx.x * 256;
  int r1 = r0 + 256; if (r1 > N) r1 = N;
  float s0 = 0.f, q0 = 0.f, s1 = 0.f, q1 = 0.f;
  for (int r = r0 + q; r < r1; r += 4) {
    unsigned u = h2b[(size_t)r * 64 + c];
    float h0 = bf16_lo(u), h1 = bf16_hi(u);
    s0 += h0; q0 = fmaf(h0, h0, q0);
    s1 += h1; q1 = fmaf(h1, h1, q1);
  }
  __shared__ float red[4][256];
  int t = threadIdx.x;
  red[0][t] = s0; red[1][t] = q0; red[2][t] = s1; red[3][t] = q1;
  __syncthreads();
  if (t < 64) {
    float S0 = red[0][t] + red[0][t + 64] + red[0][t + 128] + red[0][t + 192];
    float Q0 = red[1][t] + red[1][t + 64] + red[1][t + 128] + red[1][t + 192];
    float S1 = red[2][t] + red[2][t + 64] + red[2][t + 128] + red[2][t + 192];
    float Q1 = red[3][t] + red[3][t + 64] + red[3][t + 128] + red[3][t + 192];
    atomicAdd(&ssum[2 * t], S0);     atomicAdd(&ssum[2 * t + 1], S1);
    atomicAdd(&ssq[2 * t], Q0);      atomicAdd(&ssq[2 * t + 1], Q1);
  }
}

// -------------------- pooling (one wave per graph, 4-deep) ------------------
__global__ __launch_bounds__(256) void k_pool(const unsigned* __restrict__ h2b,
                                              const int* __restrict__ goff,
                                              const float* __restrict__ a,
                                              const float* __restrict__ c,
                                              float* __restrict__ pooled, int G) {
  int g = __builtin_amdgcn_readfirstlane((int)((blockIdx.x * 256 + threadIdx.x) >> 6));
  int lane = threadIdx.x & 63;
  if (g >= G) return;
  int r0 = goff[g], r1 = goff[g + 1];
  float s0 = 0.f, s1 = 0.f;
  int r = r0;
  while (r + 4 <= r1) {
    unsigned u0 = h2b[(size_t)(r + 0) * 64 + lane];
    unsigned u1 = h2b[(size_t)(r + 1) * 64 + lane];
    unsigned u2 = h2b[(size_t)(r + 2) * 64 + lane];
    unsigned u3 = h2b[(size_t)(r + 3) * 64 + lane];
    r += 4;
    s0 += bf16_lo(u0); s1 += bf16_hi(u0);
    s0 += bf16_lo(u1); s1 += bf16_hi(u1);
    s0 += bf16_lo(u2); s1 += bf16_hi(u2);
    s0 += bf16_lo(u3); s1 += bf16_hi(u3);
  }
  while (r < r1) {
    unsigned u = h2b[(size_t)r * 64 + lane];
    ++r;
    s0 += bf16_lo(u); s1 += bf16_hi(u);
  }
  float p0 = 0.f, p1 = 0.f;
  if (r1 > r0) {
    float inv = 1.0f / (float)(r1 - r0);
    float2 av = ((const float2*)a)[lane];
    float2 cv = ((const float2*)c)[lane];
    p0 = fmaf(av.x, s0 * inv, cv.x);
    p1 = fmaf(av.y, s1 * inv, cv.y);
  }
  *(float2*)&pooled[(size_t)g * 128 + 2 * lane] = make_float2(p0, p1);
}

// -------------------- final MLP (one wave per graph) ------------------------
__global__ __launch_bounds__(64) void k_mlp(const float* __restrict__ pooled,
                                            const float* __restrict__ hw1,
                                            const float* __restrict__ hb1,
                                            const float* __restrict__ hw2,
                                            const float* __restrict__ hb2,
                                            float* __restrict__ out, int G) {
  int g = blockIdx.x;
  int j = threadIdx.x;  // 64
  const float* p = pooled + (size_t)g * 128;
  float acc = hb1[j];
  for (int f = 0; f < 128; ++f) acc = fmaf(p[f], hw1[f * 64 + j], acc);
  acc = fmaxf(acc, 0.f) * hw2[j];
  for (int d = 32; d; d >>= 1) acc += __shfl_down(acc, d);
  if (j == 0) out[g] = acc + hb2[0];
}

// ---------------------------------------------------------------------------
extern "C" void kernel_launch(void* const* d_in, const int* in_sizes, int n_in,
                              void* d_out, int out_size, void* d_ws, size_t ws_size,
                              hipStream_t stream) {
  const float* x     = (const float*)d_in[0];
  const int*   ei    = (const int*)d_in[1];
  const int*   batch = (const int*)d_in[2];
  const float* W     = (const float*)d_in[3];
  const float* b     = (const float*)d_in[4];
  const float* gamma = (const float*)d_in[5];
  const float* beta  = (const float*)d_in[6];
  const float* hw1   = (const float*)d_in[7];
  const float* hb1   = (const float*)d_in[8];
  const float* hw2   = (const float*)d_in[9];
  const float* hb2   = (const float*)d_in[10];
  float* out = (float*)d_out;

  const int F = 128;
  const int N = in_sizes[0] / F;
  const int E = in_sizes[1] / 2;
  const int G = out_size;
  const int nbuk = (N + 127) / 128;

  const int* esrc = ei;
  const int* edst = ei + E;

  // ---- workspace carve ----
  char* wp = (char*)d_ws;
  auto alloc = [&](size_t bytes) -> void* {
    void* r = (void*)wp;
    wp += (bytes + 255) & ~(size_t)255;
    return r;
  };
  unsigned* hWb   = (unsigned*)alloc((size_t)N * 64 * 4);
  unsigned* h2b   = (unsigned*)alloc((size_t)N * 64 * 4);
  float* dis      = (float*)alloc((size_t)N * 4);
  int*   eoff     = (int*)alloc((size_t)(N + 1) * 4);
  int*   csr_src  = (int*)alloc((size_t)E * 4);
  unsigned* ebuf  = (unsigned*)alloc((size_t)E * 4);
  int*   bcnt     = (int*)alloc((size_t)NBUK_MAX * 4);
  int*   bof      = (int*)alloc((size_t)(NBUK_MAX + 1) * 4);
  int*   bcur     = (int*)alloc((size_t)NBUK_MAX * 4);
  int*   goff     = (int*)alloc((size_t)(G + 1) * 4);
  float* ssum     = (float*)alloc(128 * 4);
  float* ssq      = (float*)alloc(128 * 4);
  float* aff_a    = (float*)alloc(128 * 4);
  float* aff_c    = (float*)alloc(128 * 4);
  unsigned* Wp    = (unsigned*)alloc(32768);
  float* bias2    = (float*)alloc(128 * 4);
  float* pooled   = (float*)alloc((size_t)G * F * 4);
  (void)ws_size; (void)n_in;

  auto cdiv = [](int a_, int b_) { return (a_ + b_ - 1) / b_; };

  // ---- graph structure (once) ----
  k_zero1<<<cdiv(nbuk, 256), 256, 0, stream>>>(bcnt, nbuk);
  k_bucket_cnt<<<256, 256, 0, stream>>>(edst, bcnt, E, nbuk);
  k_bof_scan<<<1, 256, 0, stream>>>(bcnt, bof, bcur, nbuk, E);
  k_partition<<<cdiv(E, PCH), 256, 0, stream>>>(esrc, edst, bcur, ebuf, E, nbuk);
  k_bucket_csr2<<<nbuk, 256, 0, stream>>>(ebuf, bof, eoff, dis, csr_src, N, E);

  k_goff_bs<<<cdiv(G + 1, 256), 256, 0, stream>>>(batch, goff, N, G);

  // layer-0 fold (identity affine)
  k_fold<0><<<1, 256, 0, stream>>>(W, gamma, beta, ssum, ssq, Wp, bias2, aff_a, aff_c, 1.0f / (float)N);

  // ---- 3 GCN layers ----
  for (int i = 0; i < 3; ++i) {
    if (i == 0)
      k_gemm_mfma<true><<<cdiv(N, 64), 256, 0, stream>>>(x, Wp, bias2, dis, hWb, N);
    else
      k_gemm_mfma<false><<<cdiv(N, 64), 256, 0, stream>>>(h2b, Wp, bias2, dis, hWb, N);
    k_aggregate<<<cdiv(N * 64, 256), 256, 0, stream>>>(hWb, eoff, csr_src, dis,
                                                       b + (size_t)i * F, h2b, N);
    k_stats_b<<<cdiv(N, 256), 256, 0, stream>>>(h2b, ssum, ssq, N);
    if (i < 2)
      k_fold<1><<<1, 256, 0, stream>>>(W + (size_t)(i + 1) * F * F, gamma + (size_t)i * F,
                                       beta + (size_t)i * F, ssum, ssq, Wp, bias2,
                                       aff_a, aff_c, 1.0f / (float)N);
    else
      k_fold<2><<<1, 256, 0, stream>>>(W, gamma + (size_t)i * F, beta + (size_t)i * F,
                                       ssum, ssq, Wp, bias2, aff_a, aff_c, 1.0f / (float)N);
  }

  // ---- pooling + MLP ----
  k_pool<<<cdiv(G * 64, 256), 256, 0, stream>>>(h2b, goff, aff_a, aff_c, pooled, G);
  k_mlp<<<G, 64, 0, stream>>>(pooled, hw1, hb1, hw2, hb2, out, G);
}

// Round 10
// 432.584 us; speedup vs baseline: 2.4071x; 1.0164x over previous
//
#include <hip/hip_runtime.h>

// ---------------------------------------------------------------------------
// ReactionGCN: 3-layer GCN (GCNConv + BN + ReLU) -> global_mean_pool -> MLP
// bf16 activations end-to-end (fp32 accumulation):
//   - GEMM = MFMA 16x16x32 bf16, A-fragments loaded DIRECT from global as
//     two 8B halves at k-offsets {kgrp*4, 16+kgrp*4} per 32-k chunk
//   - aggregation: one wave per node, 16 bf16 row-gathers in flight
//   - CSR build: bucket counting sort, no per-edge global atomics
// ---------------------------------------------------------------------------

typedef __attribute__((ext_vector_type(8))) short short8;
typedef __attribute__((ext_vector_type(4))) float f32x4;

__device__ inline unsigned f32_to_bf16_rne(float f) {
  unsigned u = __float_as_uint(f);
  unsigned r = 0x7fffu + ((u >> 16) & 1u);
  return (u + r) >> 16;
}
__device__ inline unsigned pack2_bf16(float lo, float hi) {
  return f32_to_bf16_rne(lo) | (f32_to_bf16_rne(hi) << 16);
}
__device__ inline float bf16_lo(unsigned u) { return __uint_as_float(u << 16); }
__device__ inline float bf16_hi(unsigned u) { return __uint_as_float(u & 0xffff0000u); }

#define PCH 4096
#define NBUK_MAX 1024

__global__ __launch_bounds__(256) void k_zero1(int* __restrict__ a, int na) {
  int i = blockIdx.x * blockDim.x + threadIdx.x;
  if (i < na) a[i] = 0;
}

// -------------------- bucket counts via LDS histogram -----------------------
__global__ __launch_bounds__(256) void k_bucket_cnt(const int* __restrict__ dst,
                                                    int* __restrict__ bcnt, int E, int nbuk) {
  __shared__ int hist[NBUK_MAX];
  int t = threadIdx.x;
  for (int i = t; i < nbuk; i += 256) hist[i] = 0;
  __syncthreads();
  for (int e = blockIdx.x * 256 + t; e < E; e += gridDim.x * 256)
    atomicAdd(&hist[((unsigned)dst[e]) >> 7], 1);
  __syncthreads();
  for (int i = t; i < nbuk; i += 256) {
    int h = hist[i];
    if (h) atomicAdd(&bcnt[i], h);
  }
}

// -------------------- single-block scan: bcnt -> bof, bcur ------------------
__global__ __launch_bounds__(256) void k_bof_scan(const int* __restrict__ bcnt,
                                                  int* __restrict__ bof,
                                                  int* __restrict__ bcur, int nbuk, int E) {
  int t = threadIdx.x;
  int base = t * 4;
  int v[4]; int s = 0;
#pragma unroll
  for (int k = 0; k < 4; ++k) { v[k] = (base + k < nbuk) ? bcnt[base + k] : 0; s += v[k]; }
  int lane = t & 63, wv = t >> 6;
  int x = s;
#pragma unroll
  for (int d = 1; d < 64; d <<= 1) { int y = __shfl_up(x, d); if (lane >= d) x += y; }
  __shared__ int wsum[4];
  if (lane == 63) wsum[wv] = x;
  __syncthreads();
  int woff = 0;
  for (int w = 0; w < wv; ++w) woff += wsum[w];
  int run = woff + x - s;
#pragma unroll
  for (int k = 0; k < 4; ++k) {
    if (base + k < nbuk) { bof[base + k] = run; bcur[base + k] = run; }
    run += v[k];
  }
  if (t == 0) bof[nbuk] = E;
}

// -------------------- pass C: partition edges into bucket regions -----------
// record = (src<<7) | (dst&127); bucket = dst>>7.
__global__ __launch_bounds__(256) void k_partition(const int* __restrict__ src,
                                                   const int* __restrict__ dst,
                                                   int* __restrict__ bcur,
                                                   unsigned* __restrict__ ebuf,
                                                   int E, int nbuk) {
  __shared__ int hist[NBUK_MAX];
  __shared__ int lofs[NBUK_MAX];
  __shared__ int gbase[NBUK_MAX];
  __shared__ uint2 stage[PCH];
  int t = threadIdx.x;
  int e0 = blockIdx.x * PCH;
  int cnt = E - e0; if (cnt > PCH) cnt = PCH;
  for (int i = t; i < nbuk; i += 256) hist[i] = 0;
  __syncthreads();
  uint2 ev[PCH / 256];
#pragma unroll
  for (int k = 0; k < PCH / 256; ++k) {
    int i = t + k * 256;
    uint2 r = make_uint2(0u, 0u);
    if (i < cnt) {
      r = make_uint2((unsigned)src[e0 + i], (unsigned)dst[e0 + i]);
      atomicAdd(&hist[r.y >> 7], 1);
    }
    ev[k] = r;
  }
  __syncthreads();
  if (t < 64) {
    int run = 0;
    for (int c0 = 0; c0 < nbuk; c0 += 64) {
      int idx = c0 + t;
      int v = (idx < nbuk) ? hist[idx] : 0;
      int x = v;
#pragma unroll
      for (int dlt = 1; dlt < 64; dlt <<= 1) { int y = __shfl_up(x, dlt); if (t >= dlt) x += y; }
      if (idx < nbuk) lofs[idx] = run + x - v;
      run += __shfl(x, 63);
    }
  }
  __syncthreads();
  for (int i = t; i < nbuk; i += 256) {
    int h = hist[i];
    if (h > 0) gbase[i] = atomicAdd(&bcur[i], h);
    hist[i] = 0;
  }
  __syncthreads();
#pragma unroll
  for (int k = 0; k < PCH / 256; ++k) {
    int i = t + k * 256;
    if (i < cnt) {
      uint2 r = ev[k];
      int bk = (int)(r.y >> 7);
      unsigned packed = (r.x << 7) | (r.y & 127u);
      int rank = atomicAdd(&hist[bk], 1);
      stage[lofs[bk] + rank] = make_uint2(packed, (unsigned)bk);
    }
  }
  __syncthreads();
  for (int j = t; j < cnt; j += 256) {
    uint2 s = stage[j];
    int bk = (int)s.y;
    ebuf[(size_t)gbase[bk] + (j - lofs[bk])] = s.x;
  }
}

// -------------------- pass D: fused deg/eoff/dis + CSR placement ------------
__global__ __launch_bounds__(256) void k_bucket_csr2(const unsigned* __restrict__ ebuf,
                                                     const int* __restrict__ bof,
                                                     int* __restrict__ eoff,
                                                     float* __restrict__ dis,
                                                     int* __restrict__ csr_src, int N, int E) {
  __shared__ int lcnt[128];
  __shared__ int loff[128];
  int b = blockIdx.x;
  int n0 = b * 128;
  int t = threadIdx.x;
  int nn = N - n0; if (nn > 128) nn = 128;
  int e0 = bof[b], e1 = bof[b + 1];
  if (t < 128) lcnt[t] = 0;
  __syncthreads();
  for (int j = e0 + t; j < e1; j += 256) atomicAdd(&lcnt[ebuf[j] & 127u], 1);
  __syncthreads();
  if (t < 64) {
    int run = 0;
    for (int c0 = 0; c0 < 128; c0 += 64) {
      int v = lcnt[c0 + t];
      int x = v;
#pragma unroll
      for (int d = 1; d < 64; d <<= 1) { int y = __shfl_up(x, d); if (t >= d) x += y; }
      loff[c0 + t] = run + x - v;
      run += __shfl(x, 63);
    }
  }
  __syncthreads();
  if (t < nn) {
    eoff[n0 + t] = e0 + loff[t];
    dis[n0 + t] = 1.0f / sqrtf((float)lcnt[t] + 1.0f);
  }
  if (b == (int)gridDim.x - 1 && t == nn) eoff[n0 + nn] = E;
  __syncthreads();
  if (t < 128) lcnt[t] = 0;   // reuse as cursor
  __syncthreads();
  for (int j = e0 + t; j < e1; j += 256) {
    unsigned r = ebuf[j];
    int loc = (int)(r & 127u);
    int rank = atomicAdd(&lcnt[loc], 1);
    csr_src[e0 + loff[loc] + rank] = (int)(r >> 7);
  }
}

// -------------------- goff via binary search over sorted batch --------------
__global__ __launch_bounds__(256) void k_goff_bs(const int* __restrict__ batch,
                                                 int* __restrict__ goff, int N, int G) {
  int g = blockIdx.x * 256 + threadIdx.x;
  if (g > G) return;
  int lo = 0, hi = N;
  while (lo < hi) { int mid = (lo + hi) >> 1; if (batch[mid] < g) lo = mid + 1; else hi = mid; }
  goff[g] = lo;
}

// -------------------- fold: BN finalize + W fold + bias2 + stats zero -------
// MODE 0: identity affine, fold Wn. MODE 1: affine from stats, fold Wn.
// MODE 2: affine from stats only (no fold).
template <int MODE>
__global__ __launch_bounds__(256) void k_fold(const float* __restrict__ Wn,
                                              const float* __restrict__ gamma,
                                              const float* __restrict__ beta,
                                              float* __restrict__ ssum,
                                              float* __restrict__ ssq,
                                              unsigned* __restrict__ Wp,
                                              float* __restrict__ bias2,
                                              float* __restrict__ aff_a,
                                              float* __restrict__ aff_c,
                                              float invn) {
  __shared__ float as_[128], cs_[128], b2[128];
  int t = threadIdx.x;
  if (t < 128) {
    float a, c;
    if (MODE == 0) { a = 1.f; c = 0.f; }
    else {
      float mu  = ssum[t] * invn;
      float var = ssq[t] * invn - mu * mu;
      a = gamma[t] / sqrtf(var + 1e-5f);
      c = beta[t] - mu * a;
      ssum[t] = 0.f; ssq[t] = 0.f;
    }
    as_[t] = a; cs_[t] = c; b2[t] = 0.f;
    aff_a[t] = a; aff_c[t] = c;
  }
  __syncthreads();
  if (MODE < 2) {
#pragma unroll
    for (int it = 0; it < 8; ++it) {
      int item = it * 256 + t;
      int lane = item & 63, bk = (item >> 6) & 7, kstep = item >> 9;
      int col = bk * 16 + (lane & 15);
      int kb = kstep * 32 + ((lane >> 4) << 2);
      unsigned o[4];
      float bp = 0.f;
#pragma unroll
      for (int hh = 0; hh < 2; ++hh)
#pragma unroll
        for (int pp = 0; pp < 2; ++pp) {
          int k0 = kb + hh * 16 + pp * 2;
          float wA = Wn[(size_t)k0 * 128 + col];
          float wB = Wn[(size_t)(k0 + 1) * 128 + col];
          o[hh * 2 + pp] = pack2_bf16(as_[k0] * wA, as_[k0 + 1] * wB);
          bp = fmaf(cs_[k0], wA, fmaf(cs_[k0 + 1], wB, bp));
        }
      *(uint4*)&Wp[(size_t)item * 4] = make_uint4(o[0], o[1], o[2], o[3]);
      atomicAdd(&b2[col], bp);
    }
    __syncthreads();
    if (t < 128) bias2[t] = b2[t];
  }
}

// -------------------- MFMA GEMM: outb = bf16(dis[r] * (X @ W' + bias2)) -----
// 512 thr = 8 waves; 128 rows/block; A direct from global (two 8B halves per
// 32-k chunk: k = kk*32+kgrp*4+{0..3} and kk*32+16+kgrp*4+{0..3}); B in LDS.
template <bool AFP32>
__global__ __launch_bounds__(512) void k_gemm_mfma(const void* __restrict__ Xv,
                                                   const unsigned* __restrict__ Wp,
                                                   const float* __restrict__ bias2,
                                                   const float* __restrict__ dis,
                                                   unsigned* __restrict__ outb, int nrows) {
  __shared__ uint4 Bsm[2048];   // 32KB fragment-packed W'
  int t = threadIdx.x;
  for (int i = t; i < 2048; i += 512) Bsm[i] = ((const uint4*)Wp)[i];
  __syncthreads();
  int w = t >> 6, l = t & 63;
  int row0 = blockIdx.x * 128 + w * 16;
  int arow = row0 + (l & 15);
  int kgrp = l >> 4;
  bool aval = arow < nrows;
  f32x4 acc[8];
#pragma unroll
  for (int i = 0; i < 8; ++i) acc[i] = (f32x4){0.f, 0.f, 0.f, 0.f};
#pragma unroll
  for (int kk = 0; kk < 4; ++kk) {
    union { uint4 u; short8 s; } af;
    if (AFP32) {
      const float4* X = (const float4*)Xv;   // 32 float4 per row
      float4 v0 = make_float4(0.f, 0.f, 0.f, 0.f), v1 = v0;
      if (aval) {
        size_t bi = (size_t)arow * 32 + kk * 8 + kgrp;   // k = kk*32+kgrp*4..
        v0 = X[bi];
        v1 = X[bi + 4];                                  // k += 16
      }
      af.u = make_uint4(pack2_bf16(v0.x, v0.y), pack2_bf16(v0.z, v0.w),
                        pack2_bf16(v1.x, v1.y), pack2_bf16(v1.z, v1.w));
    } else {
      const uint2* X = (const uint2*)Xv;     // 32 uint2 per row
      uint2 lo = make_uint2(0, 0), hi = lo;
      if (aval) {
        size_t bi = (size_t)arow * 32 + kk * 8 + kgrp;   // 8B units
        lo = X[bi];
        hi = X[bi + 4];                                  // +32 bytes
      }
      af.u = make_uint4(lo.x, lo.y, hi.x, hi.y);
    }
#pragma unroll
    for (int ct = 0; ct < 8; ++ct) {
      union { uint4 u; short8 s; } bf;
      bf.u = Bsm[(kk * 8 + ct) * 64 + l];
      acc[ct] = __builtin_amdgcn_mfma_f32_16x16x32_bf16(af.s, bf.s, acc[ct], 0, 0, 0);
    }
  }
  // D[row=kgrp*4+r][col=ct*16+(l&15)]
  int dcol = l & 15;
#pragma unroll
  for (int r = 0; r < 4; ++r) {
    int grow = row0 + kgrp * 4 + r;
    if (grow < nrows) {
      float dr = dis[grow];
#pragma unroll
      for (int ct = 0; ct < 8; ++ct) {
        int col = ct * 16 + dcol;
        float v = (acc[ct][r] + bias2[col]) * dr;
        ((unsigned short*)outb)[(size_t)grow * 128 + col] = (unsigned short)f32_to_bf16_rne(v);
      }
    }
  }
}

// -------------------- aggregation (one wave per node, 16 gathers in flight) -
__global__ __launch_bounds__(256) void k_aggregate(const unsigned* __restrict__ hWb,
                                                   const int* __restrict__ eoff,
                                                   const int* __restrict__ csr_src,
                                                   const float* __restrict__ dis,
                                                   const float* __restrict__ bias,
                                                   unsigned* __restrict__ h2b, int N) {
  int node = __builtin_amdgcn_readfirstlane((int)((blockIdx.x * 256 + threadIdx.x) >> 6));
  int lane = threadIdx.x & 63;
  if (node >= N) return;
  unsigned su = hWb[(size_t)node * 64 + lane];
  float a0 = bf16_lo(su), a1 = bf16_hi(su);
  int p  = eoff[node];
  int e1 = eoff[node + 1];
  int rem = e1 - p;
  while (rem >= 16) {
    int sx[16];
#pragma unroll
    for (int k = 0; k < 16; ++k) sx[k] = csr_src[p + k];
    p += 16; rem -= 16;
    unsigned ux[16];
#pragma unroll
    for (int k = 0; k < 16; ++k) ux[k] = hWb[(size_t)sx[k] * 64 + lane];
#pragma unroll
    for (int k = 0; k < 16; ++k) { a0 += bf16_lo(ux[k]); a1 += bf16_hi(ux[k]); }
  }
  while (rem >= 4) {
    int s0 = csr_src[p], s1 = csr_src[p + 1], s2 = csr_src[p + 2], s3 = csr_src[p + 3];
    p += 4; rem -= 4;
    unsigned u0 = hWb[(size_t)s0 * 64 + lane], u1 = hWb[(size_t)s1 * 64 + lane];
    unsigned u2 = hWb[(size_t)s2 * 64 + lane], u3 = hWb[(size_t)s3 * 64 + lane];
    a0 += bf16_lo(u0); a1 += bf16_hi(u0);
    a0 += bf16_lo(u1); a1 += bf16_hi(u1);
    a0 += bf16_lo(u2); a1 += bf16_hi(u2);
    a0 += bf16_lo(u3); a1 += bf16_hi(u3);
  }
  while (rem) {
    unsigned u0 = hWb[(size_t)csr_src[p] * 64 + lane];
    ++p; --rem;
    a0 += bf16_lo(u0); a1 += bf16_hi(u0);
  }
  float dd = dis[node];
  float2 bb = ((const float2*)bias)[lane];
  float v0 = fmaf(dd, a0, bb.x);
  float v1 = fmaf(dd, a1, bb.y);
  h2b[(size_t)node * 64 + lane] = pack2_bf16(fmaxf(v0, 0.f), fmaxf(v1, 0.f));
}

// -------------------- BN stats on bf16 h2 -----------------------------------
__global__ __launch_bounds__(256) void k_stats_b(const unsigned* __restrict__ h2b,
                                                 float* __restrict__ ssum,
                                                 float* __restrict__ ssq, int N) {
  int c = threadIdx.x & 63;
  int q = threadIdx.x >> 6;
  int r0 = blockIdx.x * 256;
  int r1 = r0 + 256; if (r1 > N) r1 = N;
  float s0 = 0.f, q0 = 0.f, s1 = 0.f, q1 = 0.f;
  for (int r = r0 + q; r < r1; r += 4) {
    unsigned u = h2b[(size_t)r * 64 + c];
    float h0 = bf16_lo(u), h1 = bf16_hi(u);
    s0 += h0; q0 = fmaf(h0, h0, q0);
    s1 += h1; q1 = fmaf(h1, h1, q1);
  }
  __shared__ float red[4][256];
  int t = threadIdx.x;
  red[0][t] = s0; red[1][t] = q0; red[2][t] = s1; red[3][t] = q1;
  __syncthreads();
  if (t < 64) {
    float S0 = red[0][t] + red[0][t + 64] + red[0][t + 128] + red[0][t + 192];
    float Q0 = red[1][t] + red[1][t + 64] + red[1][t + 128] + red[1][t + 192];
    float S1 = red[2][t] + red[2][t + 64] + red[2][t + 128] + red[2][t + 192];
    float Q1 = red[3][t] + red[3][t + 64] + red[3][t + 128] + red[3][t + 192];
    atomicAdd(&ssum[2 * t], S0);     atomicAdd(&ssum[2 * t + 1], S1);
    atomicAdd(&ssq[2 * t], Q0);      atomicAdd(&ssq[2 * t + 1], Q1);
  }
}

// -------------------- pooling (one wave per graph, 4-deep) ------------------
__global__ __launch_bounds__(256) void k_pool(const unsigned* __restrict__ h2b,
                                              const int* __restrict__ goff,
                                              const float* __restrict__ a,
                                              const float* __restrict__ c,
                                              float* __restrict__ pooled, int G) {
  int g = __builtin_amdgcn_readfirstlane((int)((blockIdx.x * 256 + threadIdx.x) >> 6));
  int lane = threadIdx.x & 63;
  if (g >= G) return;
  int r0 = goff[g], r1 = goff[g + 1];
  float s0 = 0.f, s1 = 0.f;
  int r = r0;
  while (r + 4 <= r1) {
    unsigned u0 = h2b[(size_t)(r + 0) * 64 + lane];
    unsigned u1 = h2b[(size_t)(r + 1) * 64 + lane];
    unsigned u2 = h2b[(size_t)(r + 2) * 64 + lane];
    unsigned u3 = h2b[(size_t)(r + 3) * 64 + lane];
    r += 4;
    s0 += bf16_lo(u0); s1 += bf16_hi(u0);
    s0 += bf16_lo(u1); s1 += bf16_hi(u1);
    s0 += bf16_lo(u2); s1 += bf16_hi(u2);
    s0 += bf16_lo(u3); s1 += bf16_hi(u3);
  }
  while (r < r1) {
    unsigned u = h2b[(size_t)r * 64 + lane];
    ++r;
    s0 += bf16_lo(u); s1 += bf16_hi(u);
  }
  float p0 = 0.f, p1 = 0.f;
  if (r1 > r0) {
    float inv = 1.0f / (float)(r1 - r0);
    float2 av = ((const float2*)a)[lane];
    float2 cv = ((const float2*)c)[lane];
    p0 = fmaf(av.x, s0 * inv, cv.x);
    p1 = fmaf(av.y, s1 * inv, cv.y);
  }
  *(float2*)&pooled[(size_t)g * 128 + 2 * lane] = make_float2(p0, p1);
}

// -------------------- final MLP (one wave per graph) ------------------------
__global__ __launch_bounds__(64) void k_mlp(const float* __restrict__ pooled,
                                            const float* __restrict__ hw1,
                                            const float* __restrict__ hb1,
                                            const float* __restrict__ hw2,
                                            const float* __restrict__ hb2,
                                            float* __restrict__ out, int G) {
  int g = blockIdx.x;
  int j = threadIdx.x;  // 64
  const float* p = pooled + (size_t)g * 128;
  float acc = hb1[j];
  for (int f = 0; f < 128; ++f) acc = fmaf(p[f], hw1[f * 64 + j], acc);
  acc = fmaxf(acc, 0.f) * hw2[j];
  for (int d = 32; d; d >>= 1) acc += __shfl_down(acc, d);
  if (j == 0) out[g] = acc + hb2[0];
}

// ---------------------------------------------------------------------------
extern "C" void kernel_launch(void* const* d_in, const int* in_sizes, int n_in,
                              void* d_out, int out_size, void* d_ws, size_t ws_size,
                              hipStream_t stream) {
  const float* x     = (const float*)d_in[0];
  const int*   ei    = (const int*)d_in[1];
  const int*   batch = (const int*)d_in[2];
  const float* W     = (const float*)d_in[3];
  const float* b     = (const float*)d_in[4];
  const float* gamma = (const float*)d_in[5];
  const float* beta  = (const float*)d_in[6];
  const float* hw1   = (const float*)d_in[7];
  const float* hb1   = (const float*)d_in[8];
  const float* hw2   = (const float*)d_in[9];
  const float* hb2   = (const float*)d_in[10];
  float* out = (float*)d_out;

  const int F = 128;
  const int N = in_sizes[0] / F;
  const int E = in_sizes[1] / 2;
  const int G = out_size;
  const int nbuk = (N + 127) / 128;

  const int* esrc = ei;
  const int* edst = ei + E;

  // ---- workspace carve ----
  char* wp = (char*)d_ws;
  auto alloc = [&](size_t bytes) -> void* {
    void* r = (void*)wp;
    wp += (bytes + 255) & ~(size_t)255;
    return r;
  };
  unsigned* hWb   = (unsigned*)alloc((size_t)N * 64 * 4);
  unsigned* h2b   = (unsigned*)alloc((size_t)N * 64 * 4);
  float* dis      = (float*)alloc((size_t)N * 4);
  int*   eoff     = (int*)alloc((size_t)(N + 1) * 4);
  int*   csr_src  = (int*)alloc((size_t)E * 4);
  unsigned* ebuf  = (unsigned*)alloc((size_t)E * 4);
  int*   bcnt     = (int*)alloc((size_t)NBUK_MAX * 4);
  int*   bof      = (int*)alloc((size_t)(NBUK_MAX + 1) * 4);
  int*   bcur     = (int*)alloc((size_t)NBUK_MAX * 4);
  int*   goff     = (int*)alloc((size_t)(G + 1) * 4);
  float* ssum     = (float*)alloc(128 * 4);
  float* ssq      = (float*)alloc(128 * 4);
  float* aff_a    = (float*)alloc(128 * 4);
  float* aff_c    = (float*)alloc(128 * 4);
  unsigned* Wp    = (unsigned*)alloc(32768);
  float* bias2    = (float*)alloc(128 * 4);
  float* pooled   = (float*)alloc((size_t)G * F * 4);
  (void)ws_size; (void)n_in;

  auto cdiv = [](int a_, int b_) { return (a_ + b_ - 1) / b_; };

  // ---- graph structure (once) ----
  k_zero1<<<cdiv(nbuk, 256), 256, 0, stream>>>(bcnt, nbuk);
  k_bucket_cnt<<<256, 256, 0, stream>>>(edst, bcnt, E, nbuk);
  k_bof_scan<<<1, 256, 0, stream>>>(bcnt, bof, bcur, nbuk, E);
  k_partition<<<cdiv(E, PCH), 256, 0, stream>>>(esrc, edst, bcur, ebuf, E, nbuk);
  k_bucket_csr2<<<nbuk, 256, 0, stream>>>(ebuf, bof, eoff, dis, csr_src, N, E);

  k_goff_bs<<<cdiv(G + 1, 256), 256, 0, stream>>>(batch, goff, N, G);

  // layer-0 fold (identity affine)
  k_fold<0><<<1, 256, 0, stream>>>(W, gamma, beta, ssum, ssq, Wp, bias2, aff_a, aff_c, 1.0f / (float)N);

  // ---- 3 GCN layers ----
  for (int i = 0; i < 3; ++i) {
    if (i == 0)
      k_gemm_mfma<true><<<cdiv(N, 128), 512, 0, stream>>>(x, Wp, bias2, dis, hWb, N);
    else
      k_gemm_mfma<false><<<cdiv(N, 128), 512, 0, stream>>>(h2b, Wp, bias2, dis, hWb, N);
    k_aggregate<<<cdiv(N * 64, 256), 256, 0, stream>>>(hWb, eoff, csr_src, dis,
                                                       b + (size_t)i * F, h2b, N);
    k_stats_b<<<cdiv(N, 256), 256, 0, stream>>>(h2b, ssum, ssq, N);
    if (i < 2)
      k_fold<1><<<1, 256, 0, stream>>>(W + (size_t)(i + 1) * F * F, gamma + (size_t)i * F,
                                       beta + (size_t)i * F, ssum, ssq, Wp, bias2,
                                       aff_a, aff_c, 1.0f / (float)N);
    else
      k_fold<2><<<1, 256, 0, stream>>>(W, gamma + (size_t)i * F, beta + (size_t)i * F,
                                       ssum, ssq, Wp, bias2, aff_a, aff_c, 1.0f / (float)N);
  }

  // ---- pooling + MLP ----
  k_pool<<<cdiv(G * 64, 256), 256, 0, stream>>>(h2b, goff, aff_a, aff_c, pooled, G);
  k_mlp<<<G, 64, 0, stream>>>(pooled, hw1, hb1, hw2, hb2, out, G);
}

// Round 11
// 419.967 us; speedup vs baseline: 2.4794x; 1.0300x over previous
//
#include <hip/hip_runtime.h>

// ---------------------------------------------------------------------------
// ReactionGCN: 3-layer GCN (GCNConv + BN + ReLU) -> global_mean_pool -> MLP
// bf16 activations end-to-end (fp32 accumulation):
//   - GEMM = MFMA 16x16x32 bf16, A-fragments direct from global
//   - aggregation: one wave per node, 16 bf16 row-gathers in flight
//   - CSR build: bucket counting sort, no per-edge global atomics
//   - fold (BN->weights) parallelized across 8 blocks; pool+MLP fused
// ---------------------------------------------------------------------------

typedef __attribute__((ext_vector_type(8))) short short8;
typedef __attribute__((ext_vector_type(4))) float f32x4;

__device__ inline unsigned f32_to_bf16_rne(float f) {
  unsigned u = __float_as_uint(f);
  unsigned r = 0x7fffu + ((u >> 16) & 1u);
  return (u + r) >> 16;
}
__device__ inline unsigned pack2_bf16(float lo, float hi) {
  return f32_to_bf16_rne(lo) | (f32_to_bf16_rne(hi) << 16);
}
__device__ inline float bf16_lo(unsigned u) { return __uint_as_float(u << 16); }
__device__ inline float bf16_hi(unsigned u) { return __uint_as_float(u & 0xffff0000u); }

#define PCH 4096
#define NBUK_MAX 1024

__global__ __launch_bounds__(256) void k_zero2(int* __restrict__ a, int na,
                                               int* __restrict__ b, int nb) {
  int i = blockIdx.x * blockDim.x + threadIdx.x;
  if (i < na) a[i] = 0;
  if (i < nb) b[i] = 0;
}

// -------------------- bucket counts via LDS histogram -----------------------
__global__ __launch_bounds__(256) void k_bucket_cnt(const int* __restrict__ dst,
                                                    int* __restrict__ bcnt, int E, int nbuk) {
  __shared__ int hist[NBUK_MAX];
  int t = threadIdx.x;
  for (int i = t; i < nbuk; i += 256) hist[i] = 0;
  __syncthreads();
  for (int e = blockIdx.x * 256 + t; e < E; e += gridDim.x * 256)
    atomicAdd(&hist[((unsigned)dst[e]) >> 7], 1);
  __syncthreads();
  for (int i = t; i < nbuk; i += 256) {
    int h = hist[i];
    if (h) atomicAdd(&bcnt[i], h);
  }
}

// -------------------- single-block scan: bcnt -> bof, bcur ------------------
__global__ __launch_bounds__(256) void k_bof_scan(const int* __restrict__ bcnt,
                                                  int* __restrict__ bof,
                                                  int* __restrict__ bcur, int nbuk, int E) {
  int t = threadIdx.x;
  int base = t * 4;
  int v[4]; int s = 0;
#pragma unroll
  for (int k = 0; k < 4; ++k) { v[k] = (base + k < nbuk) ? bcnt[base + k] : 0; s += v[k]; }
  int lane = t & 63, wv = t >> 6;
  int x = s;
#pragma unroll
  for (int d = 1; d < 64; d <<= 1) { int y = __shfl_up(x, d); if (lane >= d) x += y; }
  __shared__ int wsum[4];
  if (lane == 63) wsum[wv] = x;
  __syncthreads();
  int woff = 0;
  for (int w = 0; w < wv; ++w) woff += wsum[w];
  int run = woff + x - s;
#pragma unroll
  for (int k = 0; k < 4; ++k) {
    if (base + k < nbuk) { bof[base + k] = run; bcur[base + k] = run; }
    run += v[k];
  }
  if (t == 0) bof[nbuk] = E;
}

// -------------------- pass C: partition edges into bucket regions -----------
// record = (src<<7) | (dst&127); bucket = dst>>7.
__global__ __launch_bounds__(256) void k_partition(const int* __restrict__ src,
                                                   const int* __restrict__ dst,
                                                   int* __restrict__ bcur,
                                                   unsigned* __restrict__ ebuf,
                                                   int E, int nbuk) {
  __shared__ int hist[NBUK_MAX];
  __shared__ int lofs[NBUK_MAX];
  __shared__ int gbase[NBUK_MAX];
  __shared__ uint2 stage[PCH];
  int t = threadIdx.x;
  int e0 = blockIdx.x * PCH;
  int cnt = E - e0; if (cnt > PCH) cnt = PCH;
  for (int i = t; i < nbuk; i += 256) hist[i] = 0;
  __syncthreads();
  uint2 ev[PCH / 256];
#pragma unroll
  for (int k = 0; k < PCH / 256; ++k) {
    int i = t + k * 256;
    uint2 r = make_uint2(0u, 0u);
    if (i < cnt) {
      r = make_uint2((unsigned)src[e0 + i], (unsigned)dst[e0 + i]);
      atomicAdd(&hist[r.y >> 7], 1);
    }
    ev[k] = r;
  }
  __syncthreads();
  if (t < 64) {
    int run = 0;
    for (int c0 = 0; c0 < nbuk; c0 += 64) {
      int idx = c0 + t;
      int v = (idx < nbuk) ? hist[idx] : 0;
      int x = v;
#pragma unroll
      for (int dlt = 1; dlt < 64; dlt <<= 1) { int y = __shfl_up(x, dlt); if (t >= dlt) x += y; }
      if (idx < nbuk) lofs[idx] = run + x - v;
      run += __shfl(x, 63);
    }
  }
  __syncthreads();
  for (int i = t; i < nbuk; i += 256) {
    int h = hist[i];
    if (h > 0) gbase[i] = atomicAdd(&bcur[i], h);
    hist[i] = 0;
  }
  __syncthreads();
#pragma unroll
  for (int k = 0; k < PCH / 256; ++k) {
    int i = t + k * 256;
    if (i < cnt) {
      uint2 r = ev[k];
      int bk = (int)(r.y >> 7);
      unsigned packed = (r.x << 7) | (r.y & 127u);
      int rank = atomicAdd(&hist[bk], 1);
      stage[lofs[bk] + rank] = make_uint2(packed, (unsigned)bk);
    }
  }
  __syncthreads();
  for (int j = t; j < cnt; j += 256) {
    uint2 s = stage[j];
    int bk = (int)s.y;
    ebuf[(size_t)gbase[bk] + (j - lofs[bk])] = s.x;
  }
}

// -------------------- pass D: fused deg/eoff/dis + CSR placement ------------
__global__ __launch_bounds__(256) void k_bucket_csr2(const unsigned* __restrict__ ebuf,
                                                     const int* __restrict__ bof,
                                                     int* __restrict__ eoff,
                                                     float* __restrict__ dis,
                                                     int* __restrict__ csr_src, int N, int E) {
  __shared__ int lcnt[128];
  __shared__ int loff[128];
  int b = blockIdx.x;
  int n0 = b * 128;
  int t = threadIdx.x;
  int nn = N - n0; if (nn > 128) nn = 128;
  int e0 = bof[b], e1 = bof[b + 1];
  if (t < 128) lcnt[t] = 0;
  __syncthreads();
  for (int j = e0 + t; j < e1; j += 256) atomicAdd(&lcnt[ebuf[j] & 127u], 1);
  __syncthreads();
  if (t < 64) {
    int run = 0;
    for (int c0 = 0; c0 < 128; c0 += 64) {
      int v = lcnt[c0 + t];
      int x = v;
#pragma unroll
      for (int d = 1; d < 64; d <<= 1) { int y = __shfl_up(x, d); if (t >= d) x += y; }
      loff[c0 + t] = run + x - v;
      run += __shfl(x, 63);
    }
  }
  __syncthreads();
  if (t < nn) {
    eoff[n0 + t] = e0 + loff[t];
    dis[n0 + t] = 1.0f / sqrtf((float)lcnt[t] + 1.0f);
  }
  if (b == (int)gridDim.x - 1 && t == nn) eoff[n0 + nn] = E;
  __syncthreads();
  if (t < 128) lcnt[t] = 0;   // reuse as cursor
  __syncthreads();
  for (int j = e0 + t; j < e1; j += 256) {
    unsigned r = ebuf[j];
    int loc = (int)(r & 127u);
    int rank = atomicAdd(&lcnt[loc], 1);
    csr_src[e0 + loff[loc] + rank] = (int)(r >> 7);
  }
}

// -------------------- goff via binary search over sorted batch --------------
__global__ __launch_bounds__(256) void k_goff_bs(const int* __restrict__ batch,
                                                 int* __restrict__ goff, int N, int G) {
  int g = blockIdx.x * 256 + threadIdx.x;
  if (g > G) return;
  int lo = 0, hi = N;
  while (lo < hi) { int mid = (lo + hi) >> 1; if (batch[mid] < g) lo = mid + 1; else hi = mid; }
  goff[g] = lo;
}

// -------------------- fold: BN finalize + W fold + bias2 (8 blocks) ---------
// MODE 0: identity affine, fold Wn (8 blocks). MODE 1: affine from stats,
// fold Wn (8 blocks). MODE 2: affine only (1 block). Block blk owns cols
// [blk*16, blk*16+16). Stats regions are per-layer (no zeroing here).
template <int MODE>
__global__ __launch_bounds__(256) void k_foldw(const float* __restrict__ Wn,
                                               const float* __restrict__ gamma,
                                               const float* __restrict__ beta,
                                               const float* __restrict__ ssum,
                                               const float* __restrict__ ssq,
                                               unsigned* __restrict__ Wp,
                                               float* __restrict__ bias2,
                                               float* __restrict__ aff_a,
                                               float* __restrict__ aff_c,
                                               float invn) {
  __shared__ float as_[128], cs_[128];
  __shared__ float b2loc[16];
  int t = threadIdx.x;
  int blk = blockIdx.x;
  if (t < 128) {
    float a, c;
    if (MODE == 0) { a = 1.f; c = 0.f; }
    else {
      float mu  = ssum[t] * invn;
      float var = ssq[t] * invn - mu * mu;
      a = gamma[t] / sqrtf(var + 1e-5f);
      c = beta[t] - mu * a;
    }
    as_[t] = a; cs_[t] = c;
    if (blk == 0) { aff_a[t] = a; aff_c[t] = c; }
  }
  if (MODE >= 2) return;
  if (t < 16) b2loc[t] = 0.f;
  __syncthreads();
  int kstep = t >> 6, lane = t & 63;
  int col = blk * 16 + (lane & 15);
  int kb = kstep * 32 + ((lane >> 4) << 2);
  unsigned o[4];
  float bp = 0.f;
#pragma unroll
  for (int hh = 0; hh < 2; ++hh)
#pragma unroll
    for (int pp = 0; pp < 2; ++pp) {
      int k0 = kb + hh * 16 + pp * 2;
      float wA = Wn[(size_t)k0 * 128 + col];
      float wB = Wn[(size_t)(k0 + 1) * 128 + col];
      o[hh * 2 + pp] = pack2_bf16(as_[k0] * wA, as_[k0 + 1] * wB);
      bp = fmaf(cs_[k0], wA, fmaf(cs_[k0 + 1], wB, bp));
    }
  *(uint4*)&Wp[((size_t)((kstep * 8 + blk) * 64 + lane)) * 4] = make_uint4(o[0], o[1], o[2], o[3]);
  atomicAdd(&b2loc[lane & 15], bp);
  __syncthreads();
  if (t < 16) bias2[blk * 16 + t] = b2loc[t];
}

// -------------------- MFMA GEMM: outb = bf16(dis[r] * (X @ W' + bias2)) -----
// 512 thr = 8 waves; 128 rows/block; A direct from global (two 8B halves per
// 32-k chunk: k = kk*32+kgrp*4+{0..3} and kk*32+16+kgrp*4+{0..3}); B in LDS.
template <bool AFP32>
__global__ __launch_bounds__(512) void k_gemm_mfma(const void* __restrict__ Xv,
                                                   const unsigned* __restrict__ Wp,
                                                   const float* __restrict__ bias2,
                                                   const float* __restrict__ dis,
                                                   unsigned* __restrict__ outb, int nrows) {
  __shared__ uint4 Bsm[2048];   // 32KB fragment-packed W'
  int t = threadIdx.x;
  for (int i = t; i < 2048; i += 512) Bsm[i] = ((const uint4*)Wp)[i];
  __syncthreads();
  int w = t >> 6, l = t & 63;
  int row0 = blockIdx.x * 128 + w * 16;
  int arow = row0 + (l & 15);
  int kgrp = l >> 4;
  bool aval = arow < nrows;
  f32x4 acc[8];
#pragma unroll
  for (int i = 0; i < 8; ++i) acc[i] = (f32x4){0.f, 0.f, 0.f, 0.f};
#pragma unroll
  for (int kk = 0; kk < 4; ++kk) {
    union { uint4 u; short8 s; } af;
    if (AFP32) {
      const float4* X = (const float4*)Xv;   // 32 float4 per row
      float4 v0 = make_float4(0.f, 0.f, 0.f, 0.f), v1 = v0;
      if (aval) {
        size_t bi = (size_t)arow * 32 + kk * 8 + kgrp;   // k = kk*32+kgrp*4..
        v0 = X[bi];
        v1 = X[bi + 4];                                  // k += 16
      }
      af.u = make_uint4(pack2_bf16(v0.x, v0.y), pack2_bf16(v0.z, v0.w),
                        pack2_bf16(v1.x, v1.y), pack2_bf16(v1.z, v1.w));
    } else {
      const uint2* X = (const uint2*)Xv;     // 32 uint2 per row
      uint2 lo = make_uint2(0, 0), hi = lo;
      if (aval) {
        size_t bi = (size_t)arow * 32 + kk * 8 + kgrp;   // 8B units
        lo = X[bi];
        hi = X[bi + 4];                                  // +32 bytes
      }
      af.u = make_uint4(lo.x, lo.y, hi.x, hi.y);
    }
#pragma unroll
    for (int ct = 0; ct < 8; ++ct) {
      union { uint4 u; short8 s; } bf;
      bf.u = Bsm[(kk * 8 + ct) * 64 + l];
      acc[ct] = __builtin_amdgcn_mfma_f32_16x16x32_bf16(af.s, bf.s, acc[ct], 0, 0, 0);
    }
  }
  // D[row=kgrp*4+r][col=ct*16+(l&15)]
  int dcol = l & 15;
#pragma unroll
  for (int r = 0; r < 4; ++r) {
    int grow = row0 + kgrp * 4 + r;
    if (grow < nrows) {
      float dr = dis[grow];
#pragma unroll
      for (int ct = 0; ct < 8; ++ct) {
        int col = ct * 16 + dcol;
        float v = (acc[ct][r] + bias2[col]) * dr;
        ((unsigned short*)outb)[(size_t)grow * 128 + col] = (unsigned short)f32_to_bf16_rne(v);
      }
    }
  }
}

// -------------------- aggregation (one wave per node, 16 gathers in flight) -
__global__ __launch_bounds__(256) void k_aggregate(const unsigned* __restrict__ hWb,
                                                   const int* __restrict__ eoff,
                                                   const int* __restrict__ csr_src,
                                                   const float* __restrict__ dis,
                                                   const float* __restrict__ bias,
                                                   unsigned* __restrict__ h2b, int N) {
  int node = __builtin_amdgcn_readfirstlane((int)((blockIdx.x * 256 + threadIdx.x) >> 6));
  int lane = threadIdx.x & 63;
  if (node >= N) return;
  unsigned su = hWb[(size_t)node * 64 + lane];
  float a0 = bf16_lo(su), a1 = bf16_hi(su);
  int p  = eoff[node];
  int e1 = eoff[node + 1];
  int rem = e1 - p;
  while (rem >= 16) {
    int sx[16];
#pragma unroll
    for (int k = 0; k < 16; ++k) sx[k] = csr_src[p + k];
    p += 16; rem -= 16;
    unsigned ux[16];
#pragma unroll
    for (int k = 0; k < 16; ++k) ux[k] = hWb[(size_t)sx[k] * 64 + lane];
#pragma unroll
    for (int k = 0; k < 16; ++k) { a0 += bf16_lo(ux[k]); a1 += bf16_hi(ux[k]); }
  }
  while (rem >= 4) {
    int s0 = csr_src[p], s1 = csr_src[p + 1], s2 = csr_src[p + 2], s3 = csr_src[p + 3];
    p += 4; rem -= 4;
    unsigned u0 = hWb[(size_t)s0 * 64 + lane], u1 = hWb[(size_t)s1 * 64 + lane];
    unsigned u2 = hWb[(size_t)s2 * 64 + lane], u3 = hWb[(size_t)s3 * 64 + lane];
    a0 += bf16_lo(u0); a1 += bf16_hi(u0);
    a0 += bf16_lo(u1); a1 += bf16_hi(u1);
    a0 += bf16_lo(u2); a1 += bf16_hi(u2);
    a0 += bf16_lo(u3); a1 += bf16_hi(u3);
  }
  while (rem) {
    unsigned u0 = hWb[(size_t)csr_src[p] * 64 + lane];
    ++p; --rem;
    a0 += bf16_lo(u0); a1 += bf16_hi(u0);
  }
  float dd = dis[node];
  float2 bb = ((const float2*)bias)[lane];
  float v0 = fmaf(dd, a0, bb.x);
  float v1 = fmaf(dd, a1, bb.y);
  h2b[(size_t)node * 64 + lane] = pack2_bf16(fmaxf(v0, 0.f), fmaxf(v1, 0.f));
}

// -------------------- BN stats on bf16 h2 (per-layer regions) ---------------
__global__ __launch_bounds__(256) void k_stats_b(const unsigned* __restrict__ h2b,
                                                 float* __restrict__ ssum,
                                                 float* __restrict__ ssq, int N) {
  int c = threadIdx.x & 63;
  int q = threadIdx.x >> 6;
  int r0 = blockIdx.x * 256;
  int r1 = r0 + 256; if (r1 > N) r1 = N;
  float s0 = 0.f, q0 = 0.f, s1 = 0.f, q1 = 0.f;
  for (int r = r0 + q; r < r1; r += 4) {
    unsigned u = h2b[(size_t)r * 64 + c];
    float h0 = bf16_lo(u), h1 = bf16_hi(u);
    s0 += h0; q0 = fmaf(h0, h0, q0);
    s1 += h1; q1 = fmaf(h1, h1, q1);
  }
  __shared__ float red[4][256];
  int t = threadIdx.x;
  red[0][t] = s0; red[1][t] = q0; red[2][t] = s1; red[3][t] = q1;
  __syncthreads();
  if (t < 64) {
    float S0 = red[0][t] + red[0][t + 64] + red[0][t + 128] + red[0][t + 192];
    float Q0 = red[1][t] + red[1][t + 64] + red[1][t + 128] + red[1][t + 192];
    float S1 = red[2][t] + red[2][t + 64] + red[2][t + 128] + red[2][t + 192];
    float Q1 = red[3][t] + red[3][t + 64] + red[3][t + 128] + red[3][t + 192];
    atomicAdd(&ssum[2 * t], S0);     atomicAdd(&ssum[2 * t + 1], S1);
    atomicAdd(&ssq[2 * t], Q0);      atomicAdd(&ssq[2 * t + 1], Q1);
  }
}

// -------------------- fused pooling + MLP (one wave per graph) --------------
__global__ __launch_bounds__(256) void k_pool_mlp(const unsigned* __restrict__ h2b,
                                                  const int* __restrict__ goff,
                                                  const float* __restrict__ a,
                                                  const float* __restrict__ c,
                                                  const float* __restrict__ hw1,
                                                  const float* __restrict__ hb1,
                                                  const float* __restrict__ hw2,
                                                  const float* __restrict__ hb2,
                                                  float* __restrict__ out, int G) {
  __shared__ float pl[4][128];
  int g = __builtin_amdgcn_readfirstlane((int)((blockIdx.x * 256 + threadIdx.x) >> 6));
  int lane = threadIdx.x & 63;
  int w = threadIdx.x >> 6;
  if (g >= G) return;
  int r0 = goff[g], r1 = goff[g + 1];
  float s0 = 0.f, s1 = 0.f;
  int r = r0;
  while (r + 4 <= r1) {
    unsigned u0 = h2b[(size_t)(r + 0) * 64 + lane];
    unsigned u1 = h2b[(size_t)(r + 1) * 64 + lane];
    unsigned u2 = h2b[(size_t)(r + 2) * 64 + lane];
    unsigned u3 = h2b[(size_t)(r + 3) * 64 + lane];
    r += 4;
    s0 += bf16_lo(u0); s1 += bf16_hi(u0);
    s0 += bf16_lo(u1); s1 += bf16_hi(u1);
    s0 += bf16_lo(u2); s1 += bf16_hi(u2);
    s0 += bf16_lo(u3); s1 += bf16_hi(u3);
  }
  while (r < r1) {
    unsigned u = h2b[(size_t)r * 64 + lane];
    ++r;
    s0 += bf16_lo(u); s1 += bf16_hi(u);
  }
  float p0 = 0.f, p1 = 0.f;
  if (r1 > r0) {
    float inv = 1.0f / (float)(r1 - r0);
    float2 av = ((const float2*)a)[lane];
    float2 cv = ((const float2*)c)[lane];
    p0 = fmaf(av.x, s0 * inv, cv.x);
    p1 = fmaf(av.y, s1 * inv, cv.y);
  }
  pl[w][2 * lane]     = p0;
  pl[w][2 * lane + 1] = p1;
  // same-wave LDS write->read: no barrier needed (lgkmcnt handled by compiler)
  float acc = hb1[lane];
  for (int f = 0; f < 128; ++f) acc = fmaf(pl[w][f], hw1[f * 64 + lane], acc);
  acc = fmaxf(acc, 0.f) * hw2[lane];
  for (int d = 32; d; d >>= 1) acc += __shfl_down(acc, d);
  if (lane == 0) out[g] = acc + hb2[0];
}

// ---------------------------------------------------------------------------
extern "C" void kernel_launch(void* const* d_in, const int* in_sizes, int n_in,
                              void* d_out, int out_size, void* d_ws, size_t ws_size,
                              hipStream_t stream) {
  const float* x     = (const float*)d_in[0];
  const int*   ei    = (const int*)d_in[1];
  const int*   batch = (const int*)d_in[2];
  const float* W     = (const float*)d_in[3];
  const float* b     = (const float*)d_in[4];
  const float* gamma = (const float*)d_in[5];
  const float* beta  = (const float*)d_in[6];
  const float* hw1   = (const float*)d_in[7];
  const float* hb1   = (const float*)d_in[8];
  const float* hw2   = (const float*)d_in[9];
  const float* hb2   = (const float*)d_in[10];
  float* out = (float*)d_out;

  const int F = 128;
  const int N = in_sizes[0] / F;
  const int E = in_sizes[1] / 2;
  const int G = out_size;
  const int nbuk = (N + 127) / 128;

  const int* esrc = ei;
  const int* edst = ei + E;

  // ---- workspace carve ----
  char* wp = (char*)d_ws;
  auto alloc = [&](size_t bytes) -> void* {
    void* r = (void*)wp;
    wp += (bytes + 255) & ~(size_t)255;
    return r;
  };
  unsigned* hWb   = (unsigned*)alloc((size_t)N * 64 * 4);
  unsigned* h2b   = (unsigned*)alloc((size_t)N * 64 * 4);
  float* dis      = (float*)alloc((size_t)N * 4);
  int*   eoff     = (int*)alloc((size_t)(N + 1) * 4);
  int*   csr_src  = (int*)alloc((size_t)E * 4);
  unsigned* ebuf  = (unsigned*)alloc((size_t)E * 4);
  int*   bcnt     = (int*)alloc((size_t)NBUK_MAX * 4);
  int*   bof      = (int*)alloc((size_t)(NBUK_MAX + 1) * 4);
  int*   bcur     = (int*)alloc((size_t)NBUK_MAX * 4);
  int*   goff     = (int*)alloc((size_t)(G + 1) * 4);
  float* stats    = (float*)alloc(768 * 4);   // 3 layers x (ssum[128]+ssq[128])
  float* aff_a    = (float*)alloc(128 * 4);
  float* aff_c    = (float*)alloc(128 * 4);
  unsigned* Wp    = (unsigned*)alloc(32768);
  float* bias2    = (float*)alloc(128 * 4);
  (void)ws_size; (void)n_in;

  auto cdiv = [](int a_, int b_) { return (a_ + b_ - 1) / b_; };

  // ---- graph structure (once) ----
  k_zero2<<<cdiv(nbuk > 768 ? nbuk : 768, 256), 256, 0, stream>>>(bcnt, nbuk, (int*)stats, 768);
  k_bucket_cnt<<<256, 256, 0, stream>>>(edst, bcnt, E, nbuk);
  k_bof_scan<<<1, 256, 0, stream>>>(bcnt, bof, bcur, nbuk, E);
  k_partition<<<cdiv(E, PCH), 256, 0, stream>>>(esrc, edst, bcur, ebuf, E, nbuk);
  k_bucket_csr2<<<nbuk, 256, 0, stream>>>(ebuf, bof, eoff, dis, csr_src, N, E);

  k_goff_bs<<<cdiv(G + 1, 256), 256, 0, stream>>>(batch, goff, N, G);

  // layer-0 fold (identity affine)
  k_foldw<0><<<8, 256, 0, stream>>>(W, gamma, beta, stats, stats, Wp, bias2, aff_a, aff_c, 1.0f / (float)N);

  // ---- 3 GCN layers ----
  for (int i = 0; i < 3; ++i) {
    float* ssum_l = stats + (size_t)i * 256;
    float* ssq_l  = ssum_l + 128;
    if (i == 0)
      k_gemm_mfma<true><<<cdiv(N, 128), 512, 0, stream>>>(x, Wp, bias2, dis, hWb, N);
    else
      k_gemm_mfma<false><<<cdiv(N, 128), 512, 0, stream>>>(h2b, Wp, bias2, dis, hWb, N);
    k_aggregate<<<cdiv(N * 64, 256), 256, 0, stream>>>(hWb, eoff, csr_src, dis,
                                                       b + (size_t)i * F, h2b, N);
    k_stats_b<<<cdiv(N, 256), 256, 0, stream>>>(h2b, ssum_l, ssq_l, N);
    if (i < 2)
      k_foldw<1><<<8, 256, 0, stream>>>(W + (size_t)(i + 1) * F * F, gamma + (size_t)i * F,
                                        beta + (size_t)i * F, ssum_l, ssq_l, Wp, bias2,
                                        aff_a, aff_c, 1.0f / (float)N);
    else
      k_foldw<2><<<1, 256, 0, stream>>>(W, gamma + (size_t)i * F, beta + (size_t)i * F,
                                        ssum_l, ssq_l, Wp, bias2, aff_a, aff_c, 1.0f / (float)N);
  }

  // ---- fused pooling + MLP ----
  k_pool_mlp<<<cdiv(G * 64, 256), 256, 0, stream>>>(h2b, goff, aff_a, aff_c,
                                                    hw1, hb1, hw2, hb2, out, G);
}